// Round 4
// baseline (115.015 us; speedup 1.0000x reference)
//
#include <hip/hip_runtime.h>
#include <math.h>

// Problem constants: B=1, S=256, HID=1024, H=16, KV=8, D=64, N_REP=2
#define SCALE 0.125f   // 1/sqrt(64)

// ---------------------------------------------------------------------------
// GEMM 1: X(256x1024) @ [Wq(1024x1024)|Wk(1024x512)|Wv(1024x512)] -> QKV partials
// K-split 2 across blocks (deterministic reduce later). 64x64 tile, 4x4 micro.
// grid = 256 (2 ksplit * 128 tiles), block = 256
// ---------------------------------------------------------------------------
__global__ __launch_bounds__(256) void gemm_qkv_kernel(
    const float* __restrict__ X, const float* __restrict__ Wq,
    const float* __restrict__ Wk, const float* __restrict__ Wv,
    float* __restrict__ Cp) {
  __shared__ float As[16][68];   // k-major: As[kk][m] so a-frag is a float4
  __shared__ float Bs[16][68];   // Bs[kk][n]
  const int bx = blockIdx.x;
  const int ks = bx >> 7;            // 0..1
  const int tile = bx & 127;         // 128 tiles: 4 m x 32 n
  const int tile_n = tile & 31, tile_m = tile >> 5;
  const int n0 = tile_n * 64, m0 = tile_m * 64;
  const float* Bp; int ldb, bc0;
  if (n0 < 1024)      { Bp = Wq; ldb = 1024; bc0 = n0; }
  else if (n0 < 1536) { Bp = Wk; ldb = 512;  bc0 = n0 - 1024; }
  else                { Bp = Wv; ldb = 512;  bc0 = n0 - 1536; }
  const int t = threadIdx.x;
  const int arow = t >> 2, akc = (t & 3) * 4;
  const int brow = t >> 4, bnc = (t & 15) * 4;
  const int ty = t >> 4, tx = t & 15;
  float acc[4][4] = {};
  const int kbeg = ks * 512, kend = kbeg + 512;
  for (int k0 = kbeg; k0 < kend; k0 += 16) {
    float4 av = *reinterpret_cast<const float4*>(X + (size_t)(m0 + arow) * 1024 + k0 + akc);
    float4 bv = *reinterpret_cast<const float4*>(Bp + (size_t)(k0 + brow) * ldb + bc0 + bnc);
    As[akc + 0][arow] = av.x; As[akc + 1][arow] = av.y;
    As[akc + 2][arow] = av.z; As[akc + 3][arow] = av.w;
    *reinterpret_cast<float4*>(&Bs[brow][bnc]) = bv;
    __syncthreads();
    #pragma unroll
    for (int kk = 0; kk < 16; ++kk) {
      float4 a = *reinterpret_cast<const float4*>(&As[kk][ty * 4]);
      float4 b = *reinterpret_cast<const float4*>(&Bs[kk][tx * 4]);
      float aa[4] = {a.x, a.y, a.z, a.w};
      float bb[4] = {b.x, b.y, b.z, b.w};
      #pragma unroll
      for (int i = 0; i < 4; ++i)
        #pragma unroll
        for (int j = 0; j < 4; ++j)
          acc[i][j] = fmaf(aa[i], bb[j], acc[i][j]);
    }
    __syncthreads();
  }
  float* Co = Cp + (size_t)ks * 524288;
  #pragma unroll
  for (int i = 0; i < 4; ++i) {
    float4 w = make_float4(acc[i][0], acc[i][1], acc[i][2], acc[i][3]);
    *reinterpret_cast<float4*>(Co + (size_t)(m0 + ty * 4 + i) * 2048 + n0 + tx * 4) = w;
  }
}

// ---------------------------------------------------------------------------
// Reduce the 2 QKV partials + apply RoPE to q (cols 0..1023) and k (1024..1535).
// v cols (1536..2047) just summed. grid = 1280, block = 256.
// ---------------------------------------------------------------------------
__global__ __launch_bounds__(256) void rope_reduce_kernel(
    const float* __restrict__ Cp, float* __restrict__ QKV,
    const float* __restrict__ cs, const float* __restrict__ sn) {
  int idx = blockIdx.x * 256 + threadIdx.x;
  const float* P0 = Cp;
  const float* P1 = Cp + 524288;
  if (idx < 196608) {                 // 256 s * 24 heads * 32 pairs
    int dp = idx & 31;
    int head = (idx >> 5) % 24;       // 0..15 q heads, 16..23 k heads
    int s = idx / 768;
    int base = s * 2048 + head * 64;
    float x1 = P0[base + dp]      + P1[base + dp];
    float x2 = P0[base + dp + 32] + P1[base + dp + 32];
    float c1 = cs[s * 64 + dp],      s1v = sn[s * 64 + dp];
    float c2 = cs[s * 64 + dp + 32], s2v = sn[s * 64 + dp + 32];
    QKV[base + dp]      = x1 * c1 - x2 * s1v;   // q' = q*cos + rot_half(q)*sin
    QKV[base + dp + 32] = x2 * c2 + x1 * s2v;
  } else {
    int i2 = idx - 196608;            // 131072 v elements
    int s = i2 >> 9, c = 1536 + (i2 & 511);
    int a = s * 2048 + c;
    QKV[a] = P0[a] + P1[a];
  }
}

// ---------------------------------------------------------------------------
// attn_weights (pre-softmax, scale applied, causal region only):
// aw[h][s][t] = scale * dot(q[h,s,:], k[g,t,:])  for t<=s.  64x64 tiles,
// lower-triangular tile enumeration. grid = 160 (16 h * 10 tiles), block = 256.
// ---------------------------------------------------------------------------
__global__ __launch_bounds__(256) void qkaw_kernel(const float* __restrict__ QKV,
                                                   float* __restrict__ aw) {
  __shared__ float Qs[64][65];
  __shared__ float Ks[64][65];
  const int SI[10] = {0,1,1,2,2,2,3,3,3,3};
  const int TI[10] = {0,0,1,0,1,2,0,1,2,3};
  int h = blockIdx.x / 10;
  int tri = blockIdx.x % 10;
  int s0 = SI[tri] * 64, t0 = TI[tri] * 64;
  int g = h >> 1;
  int t = threadIdx.x;
  #pragma unroll
  for (int i = 0; i < 4; ++i) {
    int fi = t + i * 256;             // 1024 float4 slots -> 64x64 tile
    int row = fi >> 4, c = (fi & 15) * 4;
    float4 qv = *reinterpret_cast<const float4*>(QKV + (size_t)(s0 + row) * 2048 + h * 64 + c);
    Qs[row][c] = qv.x; Qs[row][c+1] = qv.y; Qs[row][c+2] = qv.z; Qs[row][c+3] = qv.w;
    float4 kv = *reinterpret_cast<const float4*>(QKV + (size_t)(t0 + row) * 2048 + 1024 + g * 64 + c);
    Ks[row][c] = kv.x; Ks[row][c+1] = kv.y; Ks[row][c+2] = kv.z; Ks[row][c+3] = kv.w;
  }
  __syncthreads();
  int ty = t >> 4, tx = t & 15;
  float acc[4][4] = {};
  #pragma unroll
  for (int kk = 0; kk < 64; ++kk) {
    float a[4], b[4];
    #pragma unroll
    for (int i = 0; i < 4; ++i) a[i] = Qs[ty * 4 + i][kk];
    #pragma unroll
    for (int j = 0; j < 4; ++j) b[j] = Ks[tx * 4 + j][kk];
    #pragma unroll
    for (int i = 0; i < 4; ++i)
      #pragma unroll
      for (int j = 0; j < 4; ++j)
        acc[i][j] = fmaf(a[i], b[j], acc[i][j]);
  }
  for (int i = 0; i < 4; ++i) {
    int s = s0 + ty * 4 + i;
    for (int j = 0; j < 4; ++j) {
      int tt = t0 + tx * 4 + j;
      if (tt <= s) aw[((size_t)h * 256 + s) * 256 + tt] = acc[i][j] * SCALE;
    }
  }
}

// ---------------------------------------------------------------------------
// p = softmax(aw) per row; writes zeros for t>s; also P2[h,s] = sum_t p^2.
// one wave per row. grid = 1024, block = 256 (4 waves).
// ---------------------------------------------------------------------------
__global__ __launch_bounds__(256) void softmax_kernel(const float* __restrict__ aw,
    float* __restrict__ pOut, float* __restrict__ P2) {
  int wid = blockIdx.x * 4 + (threadIdx.x >> 6);   // row id 0..4095 (h*256+s)
  int lane = threadIdx.x & 63;
  int s = wid & 255;
  const float* row = aw + (size_t)wid * 256;
  float v[4], m = -3.0e38f;
  #pragma unroll
  for (int i = 0; i < 4; ++i) {
    int tt = lane + i * 64;
    v[i] = (tt <= s) ? row[tt] : -3.0e38f;
    m = fmaxf(m, v[i]);
  }
  #pragma unroll
  for (int off = 32; off; off >>= 1) m = fmaxf(m, __shfl_xor(m, off));
  float e[4], sum = 0.f;
  #pragma unroll
  for (int i = 0; i < 4; ++i) {
    int tt = lane + i * 64;
    e[i] = (tt <= s) ? __expf(v[i] - m) : 0.f;
    sum += e[i];
  }
  #pragma unroll
  for (int off = 32; off; off >>= 1) sum += __shfl_xor(sum, off);
  float inv = 1.f / sum;
  float p2 = 0.f;
  #pragma unroll
  for (int i = 0; i < 4; ++i) {
    float pv = e[i] * inv;
    pOut[(size_t)wid * 256 + lane + i * 64] = pv;
    p2 = fmaf(pv, pv, p2);
  }
  #pragma unroll
  for (int off = 32; off; off >>= 1) p2 += __shfl_xor(p2, off);
  if (lane == 0) P2[wid] = p2;
}

// ---------------------------------------------------------------------------
// The fused p_diff / qk_importance kernel.
// For each (h,s,d): z_t = scale*aw[t] - (scale*q_d)*k[t,d];
//   sum_t(p_diff-p)^2 = S2/S1^2 - 2*S3/S1 + sum_t p^2,
//   S1=sum e^z, S2=sum e^{2z}, S3=sum e^z p_t.  (|z|<~3 -> no max needed.)
// wave = one (h,row-pair); lane = d. K-head staged in LDS. Rows paired
// (j, 255-j) for triangular balance. grid = 512 (8 g * 64 u), block = 256.
// ---------------------------------------------------------------------------
__global__ __launch_bounds__(256) void pdiff_kernel(
    const float* __restrict__ QKV, const float* __restrict__ aw,
    const float* __restrict__ p, const float* __restrict__ P2,
    float* __restrict__ qkpart) {
  __shared__ float ksh[256 * 64];      // 64 KB: k[g][t][d]
  __shared__ float2 rb[4][2][256];     // 16 KB: per wave, per row: (scale*aw_t, p_t)
  int g = blockIdx.x >> 6;
  int u = blockIdx.x & 63;
  int t = threadIdx.x;
  #pragma unroll
  for (int i = 0; i < 16; ++i) {
    int fi = t + i * 256;              // 4096 float4 slots
    int tt = fi >> 4, c = (fi & 15) * 4;
    float4 kv = *reinterpret_cast<const float4*>(QKV + (size_t)tt * 2048 + 1024 + g * 64 + c);
    *reinterpret_cast<float4*>(&ksh[tt * 64 + c]) = kv;
  }
  int w = t >> 6, lane = t & 63;
  int h = 2 * g + (w & 1);
  int j = 2 * u + (w >> 1);
  for (int r = 0; r < 2; ++r) {
    int s = r ? 255 - j : j;
    const float* awRow = aw + ((size_t)h * 256 + s) * 256;
    const float* pRow  = p  + ((size_t)h * 256 + s) * 256;
    #pragma unroll
    for (int i = 0; i < 4; ++i) {
      int idx = lane + i * 64;
      rb[w][r][idx] = make_float2(awRow[idx] * SCALE, pRow[idx]);
    }
  }
  __syncthreads();
  float acc = 0.f;
  for (int r = 0; r < 2; ++r) {
    int s = r ? 255 - j : j;
    float cd = SCALE * QKV[(size_t)s * 2048 + h * 64 + lane];
    float S1 = 0.f, S2 = 0.f, S3 = 0.f;
    const float2* rbr = rb[w][r];
    for (int tt = 0; tt <= s; ++tt) {
      float kv = ksh[tt * 64 + lane];
      float2 ap = rbr[tt];
      float z = fmaf(-cd, kv, ap.x);
      float e = __expf(z);
      S1 += e;
      S2 = fmaf(e, e, S2);
      S3 = fmaf(e, ap.y, S3);
    }
    float inv = 1.f / S1;
    acc += S2 * inv * inv - 2.f * S3 * inv + P2[h * 256 + s];
  }
  qkpart[((size_t)h * 128 + j) * 64 + lane] = acc;
}

// ---------------------------------------------------------------------------
// attn_out[s][h*64+d] = sum_t p[h,s,t] * v[g,t,d].  Same wave layout as pdiff,
// v-head staged in LDS. grid = 512, block = 256.
// ---------------------------------------------------------------------------
__global__ __launch_bounds__(256) void attnv_kernel(
    const float* __restrict__ QKV, const float* __restrict__ p,
    float* __restrict__ attn_out) {
  __shared__ float vsh[256 * 64];
  int g = blockIdx.x >> 6;
  int u = blockIdx.x & 63;
  int t = threadIdx.x;
  #pragma unroll
  for (int i = 0; i < 16; ++i) {
    int fi = t + i * 256;
    int tt = fi >> 4, c = (fi & 15) * 4;
    float4 vv = *reinterpret_cast<const float4*>(QKV + (size_t)tt * 2048 + 1536 + g * 64 + c);
    *reinterpret_cast<float4*>(&vsh[tt * 64 + c]) = vv;
  }
  __syncthreads();
  int w = t >> 6, lane = t & 63;
  int h = 2 * g + (w & 1);
  int j = 2 * u + (w >> 1);
  for (int r = 0; r < 2; ++r) {
    int s = r ? 255 - j : j;
    const float* pRow = p + ((size_t)h * 256 + s) * 256;
    float acc = 0.f;
    for (int tt = 0; tt <= s; ++tt)
      acc = fmaf(pRow[tt], vsh[tt * 64 + lane], acc);
    attn_out[(size_t)s * 1024 + h * 64 + lane] = acc;
  }
}

// qk_importance[h*64+d] = sum_j qkpart[h][j][d]. grid = 4, block = 256.
__global__ __launch_bounds__(256) void qkred_kernel(const float* __restrict__ qkpart,
                                                    float* __restrict__ qkout) {
  int idx = blockIdx.x * 256 + threadIdx.x;   // 1024 = h*64+d
  int h = idx >> 6, d = idx & 63;
  float sum = 0.f;
  for (int j = 0; j < 128; ++j) sum += qkpart[((size_t)h * 128 + j) * 64 + d];
  qkout[idx] = sum;
}

// v_importance[c] = sum_s |attn_out[s][c]|; o_importance = copy. grid=4.
__global__ __launch_bounds__(256) void vimp_kernel(const float* __restrict__ attn_out,
    float* __restrict__ vout, float* __restrict__ oout) {
  int c = blockIdx.x * 256 + threadIdx.x;     // 1024
  float sum = 0.f;
  for (int s = 0; s < 256; ++s) sum += fabsf(attn_out[(size_t)s * 1024 + c]);
  vout[c] = sum;
  oout[c] = sum;
}

// ---------------------------------------------------------------------------
// GEMM 2: attn_out(256x1024) @ Wo(1024x1024) -> out partials, K-split 4.
// grid = 256 (4 ksplit * 64 tiles), block = 256.
// ---------------------------------------------------------------------------
__global__ __launch_bounds__(256) void gemm_o_kernel(
    const float* __restrict__ A, const float* __restrict__ W,
    float* __restrict__ Cp) {
  __shared__ float As[16][68];
  __shared__ float Bs[16][68];
  const int bx = blockIdx.x;
  const int ks = bx >> 6;            // 0..3
  const int tile = bx & 63;          // 64 tiles: 4 m x 16 n
  const int tile_n = tile & 15, tile_m = tile >> 4;
  const int n0 = tile_n * 64, m0 = tile_m * 64;
  const int t = threadIdx.x;
  const int arow = t >> 2, akc = (t & 3) * 4;
  const int brow = t >> 4, bnc = (t & 15) * 4;
  const int ty = t >> 4, tx = t & 15;
  float acc[4][4] = {};
  const int kbeg = ks * 256, kend = kbeg + 256;
  for (int k0 = kbeg; k0 < kend; k0 += 16) {
    float4 av = *reinterpret_cast<const float4*>(A + (size_t)(m0 + arow) * 1024 + k0 + akc);
    float4 bv = *reinterpret_cast<const float4*>(W + (size_t)(k0 + brow) * 1024 + n0 + bnc);
    As[akc + 0][arow] = av.x; As[akc + 1][arow] = av.y;
    As[akc + 2][arow] = av.z; As[akc + 3][arow] = av.w;
    *reinterpret_cast<float4*>(&Bs[brow][bnc]) = bv;
    __syncthreads();
    #pragma unroll
    for (int kk = 0; kk < 16; ++kk) {
      float4 a = *reinterpret_cast<const float4*>(&As[kk][ty * 4]);
      float4 b = *reinterpret_cast<const float4*>(&Bs[kk][tx * 4]);
      float aa[4] = {a.x, a.y, a.z, a.w};
      float bb[4] = {b.x, b.y, b.z, b.w};
      #pragma unroll
      for (int i = 0; i < 4; ++i)
        #pragma unroll
        for (int j = 0; j < 4; ++j)
          acc[i][j] = fmaf(aa[i], bb[j], acc[i][j]);
    }
    __syncthreads();
  }
  float* Co = Cp + (size_t)ks * 262144;
  #pragma unroll
  for (int i = 0; i < 4; ++i) {
    float4 w = make_float4(acc[i][0], acc[i][1], acc[i][2], acc[i][3]);
    *reinterpret_cast<float4*>(Co + (size_t)(m0 + ty * 4 + i) * 1024 + n0 + tx * 4) = w;
  }
}

// out = sum of 4 partials. grid = 1024.
__global__ __launch_bounds__(256) void o_reduce_kernel(const float* __restrict__ Op,
                                                       float* __restrict__ out) {
  int i = blockIdx.x * 256 + threadIdx.x;     // 262144
  out[i] = Op[i] + Op[262144 + i] + Op[524288 + i] + Op[786432 + i];
}

// ---------------------------------------------------------------------------
extern "C" void kernel_launch(void* const* d_in, const int* in_sizes, int n_in,
                              void* d_out, int out_size, void* d_ws, size_t ws_size,
                              hipStream_t stream) {
  const float* X    = (const float*)d_in[0];   // hidden_states (1,256,1024)
  const float* cosp = (const float*)d_in[1];   // (1,256,64)
  const float* sinp = (const float*)d_in[2];   // (1,256,64)
  // d_in[3] attention_mask: causal, implemented analytically
  const float* Wq   = (const float*)d_in[4];   // (1024,1024)
  const float* Wk   = (const float*)d_in[5];   // (1024,512)
  const float* Wv   = (const float*)d_in[6];   // (1024,512)
  const float* Wo   = (const float*)d_in[7];   // (1024,1024)

  float* out  = (float*)d_out;                 // 262144
  float* pOut = out + 262144;                  // 1048576
  float* qki  = pOut + 1048576;                // 1024
  float* vi   = qki + 1024;                    // 1024
  float* oi   = vi + 1024;                     // 1024

  float* ws       = (float*)d_ws;
  float* QKV      = ws;                        // 524288  (s-major, 2048 cols: q|k|v)
  float* aw       = ws + 524288;               // 1048576
  float* P2       = ws + 1572864;              // 4096
  float* attn_out = ws + 1576960;              // 262144
  float* qkpart   = ws + 1839104;              // 131072
  float* scratch  = ws + 1970176;              // 1048576 (QKV partials, reused for O partials)

  hipLaunchKernelGGL(gemm_qkv_kernel, dim3(256), dim3(256), 0, stream, X, Wq, Wk, Wv, scratch);
  hipLaunchKernelGGL(rope_reduce_kernel, dim3(1280), dim3(256), 0, stream, scratch, QKV, cosp, sinp);
  hipLaunchKernelGGL(qkaw_kernel, dim3(160), dim3(256), 0, stream, QKV, aw);
  hipLaunchKernelGGL(softmax_kernel, dim3(1024), dim3(256), 0, stream, aw, pOut, P2);
  hipLaunchKernelGGL(pdiff_kernel, dim3(512), dim3(256), 0, stream, QKV, aw, pOut, P2, qkpart);
  hipLaunchKernelGGL(attnv_kernel, dim3(512), dim3(256), 0, stream, QKV, pOut, attn_out);
  hipLaunchKernelGGL(qkred_kernel, dim3(4), dim3(256), 0, stream, qkpart, qki);
  hipLaunchKernelGGL(vimp_kernel, dim3(4), dim3(256), 0, stream, attn_out, vi, oi);
  hipLaunchKernelGGL(gemm_o_kernel, dim3(256), dim3(256), 0, stream, attn_out, Wo, scratch);
  hipLaunchKernelGGL(o_reduce_kernel, dim3(1024), dim3(256), 0, stream, scratch, out);
}

// Round 5
// 89.615 us; speedup vs baseline: 1.2834x; 1.2834x over previous
//
#include <hip/hip_runtime.h>
#include <math.h>

// Problem constants: B=1, S=256, HID=1024, H=16, KV=8, D=64, N_REP=2
#define SCALE 0.125f   // 1/sqrt(64)

// ---------------------------------------------------------------------------
// GEMM 1: X(256x1024) @ [Wq|Wk|Wv] -> QKV partials, K-split 4.
// 64x64 tile, 4x4 micro, register-staged double buffer.
// grid = 512 (4 ksplit * 128 tiles), block = 256
// ---------------------------------------------------------------------------
__global__ __launch_bounds__(256) void gemm_qkv_kernel(
    const float* __restrict__ X, const float* __restrict__ Wq,
    const float* __restrict__ Wk, const float* __restrict__ Wv,
    float* __restrict__ Cp) {
  __shared__ float As[16][68];   // k-major: As[kk][m]
  __shared__ float Bs[16][68];   // Bs[kk][n]
  const int bx = blockIdx.x;
  const int ks = bx >> 7;            // 0..3
  const int tile = bx & 127;         // 128 tiles: 4 m x 32 n
  const int tile_n = tile & 31, tile_m = tile >> 5;
  const int n0 = tile_n * 64, m0 = tile_m * 64;
  const float* Bp; int ldb, bc0;
  if (n0 < 1024)      { Bp = Wq; ldb = 1024; bc0 = n0; }
  else if (n0 < 1536) { Bp = Wk; ldb = 512;  bc0 = n0 - 1024; }
  else                { Bp = Wv; ldb = 512;  bc0 = n0 - 1536; }
  const int t = threadIdx.x;
  const int arow = t >> 2, akc = (t & 3) * 4;
  const int brow = t >> 4, bnc = (t & 15) * 4;
  const int ty = t >> 4, tx = t & 15;
  float acc[4][4] = {};
  const int kbeg = ks * 256, kend = kbeg + 256;
  float4 av = *reinterpret_cast<const float4*>(X + (size_t)(m0 + arow) * 1024 + kbeg + akc);
  float4 bv = *reinterpret_cast<const float4*>(Bp + (size_t)(kbeg + brow) * ldb + bc0 + bnc);
  for (int k0 = kbeg; k0 < kend; k0 += 16) {
    As[akc + 0][arow] = av.x; As[akc + 1][arow] = av.y;
    As[akc + 2][arow] = av.z; As[akc + 3][arow] = av.w;
    *reinterpret_cast<float4*>(&Bs[brow][bnc]) = bv;
    __syncthreads();
    float4 av2, bv2;
    if (k0 + 16 < kend) {   // issue next-tile loads; latency hides under compute
      av2 = *reinterpret_cast<const float4*>(X + (size_t)(m0 + arow) * 1024 + k0 + 16 + akc);
      bv2 = *reinterpret_cast<const float4*>(Bp + (size_t)(k0 + 16 + brow) * ldb + bc0 + bnc);
    }
    #pragma unroll
    for (int kk = 0; kk < 16; ++kk) {
      float4 a = *reinterpret_cast<const float4*>(&As[kk][ty * 4]);
      float4 b = *reinterpret_cast<const float4*>(&Bs[kk][tx * 4]);
      float aa[4] = {a.x, a.y, a.z, a.w};
      float bb[4] = {b.x, b.y, b.z, b.w};
      #pragma unroll
      for (int i = 0; i < 4; ++i)
        #pragma unroll
        for (int j = 0; j < 4; ++j)
          acc[i][j] = fmaf(aa[i], bb[j], acc[i][j]);
    }
    __syncthreads();
    av = av2; bv = bv2;
  }
  float* Co = Cp + (size_t)ks * 524288;
  #pragma unroll
  for (int i = 0; i < 4; ++i) {
    float4 w = make_float4(acc[i][0], acc[i][1], acc[i][2], acc[i][3]);
    *reinterpret_cast<float4*>(Co + (size_t)(m0 + ty * 4 + i) * 2048 + n0 + tx * 4) = w;
  }
}

// ---------------------------------------------------------------------------
// Reduce the 4 QKV partials + apply RoPE to q (cols 0..1023) and k (1024..1535).
// v cols (1536..2047) just summed. grid = 1280, block = 256.
// ---------------------------------------------------------------------------
__global__ __launch_bounds__(256) void rope_reduce_kernel(
    const float* __restrict__ Cp, float* __restrict__ QKV,
    const float* __restrict__ cs, const float* __restrict__ sn) {
  int idx = blockIdx.x * 256 + threadIdx.x;
  const float* P0 = Cp;
  const float* P1 = Cp + 524288;
  const float* P2p = Cp + 1048576;
  const float* P3 = Cp + 1572864;
  if (idx < 196608) {                 // 256 s * 24 heads * 32 pairs
    int dp = idx & 31;
    int head = (idx >> 5) % 24;       // 0..15 q heads, 16..23 k heads
    int s = idx / 768;
    int base = s * 2048 + head * 64;
    int a1 = base + dp, a2 = base + dp + 32;
    float x1 = P0[a1] + P1[a1] + P2p[a1] + P3[a1];
    float x2 = P0[a2] + P1[a2] + P2p[a2] + P3[a2];
    float c1 = cs[s * 64 + dp],      s1v = sn[s * 64 + dp];
    float c2 = cs[s * 64 + dp + 32], s2v = sn[s * 64 + dp + 32];
    QKV[a1] = x1 * c1 - x2 * s1v;   // q' = q*cos + rot_half(q)*sin
    QKV[a2] = x2 * c2 + x1 * s2v;
  } else {
    int i2 = idx - 196608;            // 131072 v elements
    int s = i2 >> 9, c = 1536 + (i2 & 511);
    int a = s * 2048 + c;
    QKV[a] = P0[a] + P1[a] + P2p[a] + P3[a];
  }
}

// ---------------------------------------------------------------------------
// attn_weights (pre-softmax, scale applied, causal region only).
// k-major LDS (stride 68 keeps float4 16B-aligned) -> ds_read_b128 fragments.
// grid = 160 (16 h * 10 lower-tri tiles), block = 256.
// ---------------------------------------------------------------------------
__global__ __launch_bounds__(256, 2) void qkaw_kernel(const float* __restrict__ QKV,
                                                      float* __restrict__ aw) {
  __shared__ float Qs[64][68];   // Qs[d][m]
  __shared__ float Ks[64][68];   // Ks[d][n]
  int h = blockIdx.x / 10;
  int tri = blockIdx.x % 10;
  int si = (tri >= 6) ? 3 : ((tri >= 3) ? 2 : ((tri >= 1) ? 1 : 0));
  int ti = tri - ((si * (si + 1)) >> 1);
  int s0 = si * 64, t0 = ti * 64;
  int g = h >> 1;
  int t = threadIdx.x;
  #pragma unroll
  for (int i = 0; i < 4; ++i) {
    int fi = t + i * 256;             // 1024 float4 slots -> 64x64 tile
    int row = fi >> 4, c = (fi & 15) * 4;
    float4 qv = *reinterpret_cast<const float4*>(QKV + (size_t)(s0 + row) * 2048 + h * 64 + c);
    Qs[c + 0][row] = qv.x; Qs[c + 1][row] = qv.y;
    Qs[c + 2][row] = qv.z; Qs[c + 3][row] = qv.w;
    float4 kv = *reinterpret_cast<const float4*>(QKV + (size_t)(t0 + row) * 2048 + 1024 + g * 64 + c);
    Ks[c + 0][row] = kv.x; Ks[c + 1][row] = kv.y;
    Ks[c + 2][row] = kv.z; Ks[c + 3][row] = kv.w;
  }
  __syncthreads();
  int ty = t >> 4, tx = t & 15;
  float acc[4][4] = {};
  #pragma unroll 8
  for (int kk = 0; kk < 64; ++kk) {
    float4 a = *reinterpret_cast<const float4*>(&Qs[kk][ty * 4]);
    float4 b = *reinterpret_cast<const float4*>(&Ks[kk][tx * 4]);
    float aa[4] = {a.x, a.y, a.z, a.w};
    float bb[4] = {b.x, b.y, b.z, b.w};
    #pragma unroll
    for (int i = 0; i < 4; ++i)
      #pragma unroll
      for (int j = 0; j < 4; ++j)
        acc[i][j] = fmaf(aa[i], bb[j], acc[i][j]);
  }
  for (int i = 0; i < 4; ++i) {
    int s = s0 + ty * 4 + i;
    for (int j = 0; j < 4; ++j) {
      int tt = t0 + tx * 4 + j;
      if (tt <= s) aw[((size_t)h * 256 + s) * 256 + tt] = acc[i][j] * SCALE;
    }
  }
}

// ---------------------------------------------------------------------------
// p = softmax(aw) per row; writes zeros for t>s; also P2[h,s] = sum_t p^2.
// one wave per row. grid = 1024, block = 256 (4 waves).
// ---------------------------------------------------------------------------
__global__ __launch_bounds__(256) void softmax_kernel(const float* __restrict__ aw,
    float* __restrict__ pOut, float* __restrict__ P2) {
  int wid = blockIdx.x * 4 + (threadIdx.x >> 6);   // row id 0..4095 (h*256+s)
  int lane = threadIdx.x & 63;
  int s = wid & 255;
  const float* row = aw + (size_t)wid * 256;
  float v[4], m = -3.0e38f;
  #pragma unroll
  for (int i = 0; i < 4; ++i) {
    int tt = lane + i * 64;
    v[i] = (tt <= s) ? row[tt] : -3.0e38f;
    m = fmaxf(m, v[i]);
  }
  #pragma unroll
  for (int off = 32; off; off >>= 1) m = fmaxf(m, __shfl_xor(m, off));
  float e[4], sum = 0.f;
  #pragma unroll
  for (int i = 0; i < 4; ++i) {
    int tt = lane + i * 64;
    e[i] = (tt <= s) ? __expf(v[i] - m) : 0.f;
    sum += e[i];
  }
  #pragma unroll
  for (int off = 32; off; off >>= 1) sum += __shfl_xor(sum, off);
  float inv = 1.f / sum;
  float p2 = 0.f;
  #pragma unroll
  for (int i = 0; i < 4; ++i) {
    float pv = e[i] * inv;
    pOut[(size_t)wid * 256 + lane + i * 64] = pv;
    p2 = fmaf(pv, pv, p2);
  }
  #pragma unroll
  for (int off = 32; off; off >>= 1) p2 += __shfl_xor(p2, off);
  if (lane == 0) P2[wid] = p2;
}

// ---------------------------------------------------------------------------
// The fused p_diff / qk_importance kernel.
// For each (h,s,d): z_t = scale*aw[t] - (scale*q_d)*k[t,d];
//   sum_t(p_diff-p)^2 = S2/S1^2 - 2*S3/S1 + sum_t p^2,
//   S1=sum e^z, S2=sum e^{2z}, S3=sum e^z p_t.  (|z|<~3 -> no max needed.)
// wave = one (h,row-pair); lane = d. K-head staged in LDS. Rows paired
// (j, 255-j) for triangular balance. grid = 512 (8 g * 64 u), block = 256.
// ---------------------------------------------------------------------------
__global__ __launch_bounds__(256) void pdiff_kernel(
    const float* __restrict__ QKV, const float* __restrict__ aw,
    const float* __restrict__ p, const float* __restrict__ P2,
    float* __restrict__ qkpart) {
  __shared__ float ksh[256 * 64];      // 64 KB: k[g][t][d]
  __shared__ float2 rb[4][2][256];     // 16 KB: per wave, per row: (scale*aw_t, p_t)
  int g = blockIdx.x >> 6;
  int u = blockIdx.x & 63;
  int t = threadIdx.x;
  #pragma unroll
  for (int i = 0; i < 16; ++i) {
    int fi = t + i * 256;              // 4096 float4 slots
    int tt = fi >> 4, c = (fi & 15) * 4;
    float4 kv = *reinterpret_cast<const float4*>(QKV + (size_t)tt * 2048 + 1024 + g * 64 + c);
    *reinterpret_cast<float4*>(&ksh[tt * 64 + c]) = kv;
  }
  int w = t >> 6, lane = t & 63;
  int h = 2 * g + (w & 1);
  int j = 2 * u + (w >> 1);
  for (int r = 0; r < 2; ++r) {
    int s = r ? 255 - j : j;
    const float* awRow = aw + ((size_t)h * 256 + s) * 256;
    const float* pRow  = p  + ((size_t)h * 256 + s) * 256;
    #pragma unroll
    for (int i = 0; i < 4; ++i) {
      int idx = lane + i * 64;
      rb[w][r][idx] = make_float2(awRow[idx] * SCALE, pRow[idx]);
    }
  }
  __syncthreads();
  float acc = 0.f;
  for (int r = 0; r < 2; ++r) {
    int s = r ? 255 - j : j;
    float cd = SCALE * QKV[(size_t)s * 2048 + h * 64 + lane];
    float S1 = 0.f, S2 = 0.f, S3 = 0.f;
    const float2* rbr = rb[w][r];
    for (int tt = 0; tt <= s; ++tt) {
      float kv = ksh[tt * 64 + lane];
      float2 ap = rbr[tt];
      float z = fmaf(-cd, kv, ap.x);
      float e = __expf(z);
      S1 += e;
      S2 = fmaf(e, e, S2);
      S3 = fmaf(e, ap.y, S3);
    }
    float inv = 1.f / S1;
    acc += S2 * inv * inv - 2.f * S3 * inv + P2[h * 256 + s];
  }
  qkpart[((size_t)h * 128 + j) * 64 + lane] = acc;
}

// ---------------------------------------------------------------------------
// attn_out[s][h*64+d] = sum_t p[h,s,t] * v[g,t,d].  Same wave layout as pdiff,
// v-head staged in LDS. grid = 512, block = 256.
// ---------------------------------------------------------------------------
__global__ __launch_bounds__(256) void attnv_kernel(
    const float* __restrict__ QKV, const float* __restrict__ p,
    float* __restrict__ attn_out) {
  __shared__ float vsh[256 * 64];
  int g = blockIdx.x >> 6;
  int u = blockIdx.x & 63;
  int t = threadIdx.x;
  #pragma unroll
  for (int i = 0; i < 16; ++i) {
    int fi = t + i * 256;
    int tt = fi >> 4, c = (fi & 15) * 4;
    float4 vv = *reinterpret_cast<const float4*>(QKV + (size_t)tt * 2048 + 1536 + g * 64 + c);
    *reinterpret_cast<float4*>(&vsh[tt * 64 + c]) = vv;
  }
  __syncthreads();
  int w = t >> 6, lane = t & 63;
  int h = 2 * g + (w & 1);
  int j = 2 * u + (w >> 1);
  for (int r = 0; r < 2; ++r) {
    int s = r ? 255 - j : j;
    const float* pRow = p + ((size_t)h * 256 + s) * 256;
    float acc = 0.f;
    for (int tt = 0; tt <= s; ++tt)
      acc = fmaf(pRow[tt], vsh[tt * 64 + lane], acc);
    attn_out[(size_t)s * 1024 + h * 64 + lane] = acc;
  }
}

// qk_importance[h*64+d] = sum_j qkpart[h][j][d]. grid = 4, block = 256.
__global__ __launch_bounds__(256) void qkred_kernel(const float* __restrict__ qkpart,
                                                    float* __restrict__ qkout) {
  int idx = blockIdx.x * 256 + threadIdx.x;   // 1024 = h*64+d
  int h = idx >> 6, d = idx & 63;
  float sum = 0.f;
  for (int j = 0; j < 128; ++j) sum += qkpart[((size_t)h * 128 + j) * 64 + d];
  qkout[idx] = sum;
}

// v_importance[c] = sum_s |attn_out[s][c]|; o_importance = copy. grid=4.
__global__ __launch_bounds__(256) void vimp_kernel(const float* __restrict__ attn_out,
    float* __restrict__ vout, float* __restrict__ oout) {
  int c = blockIdx.x * 256 + threadIdx.x;     // 1024
  float sum = 0.f;
  for (int s = 0; s < 256; ++s) sum += fabsf(attn_out[(size_t)s * 1024 + c]);
  vout[c] = sum;
  oout[c] = sum;
}

// ---------------------------------------------------------------------------
// GEMM 2: attn_out(256x1024) @ Wo(1024x1024) -> out partials, K-split 4,
// register-staged double buffer. grid = 256 (4 ksplit * 64 tiles), block = 256.
// ---------------------------------------------------------------------------
__global__ __launch_bounds__(256) void gemm_o_kernel(
    const float* __restrict__ A, const float* __restrict__ W,
    float* __restrict__ Cp) {
  __shared__ float As[16][68];
  __shared__ float Bs[16][68];
  const int bx = blockIdx.x;
  const int ks = bx >> 6;            // 0..3
  const int tile = bx & 63;          // 64 tiles: 4 m x 16 n
  const int tile_n = tile & 15, tile_m = tile >> 4;
  const int n0 = tile_n * 64, m0 = tile_m * 64;
  const int t = threadIdx.x;
  const int arow = t >> 2, akc = (t & 3) * 4;
  const int brow = t >> 4, bnc = (t & 15) * 4;
  const int ty = t >> 4, tx = t & 15;
  float acc[4][4] = {};
  const int kbeg = ks * 256, kend = kbeg + 256;
  float4 av = *reinterpret_cast<const float4*>(A + (size_t)(m0 + arow) * 1024 + kbeg + akc);
  float4 bv = *reinterpret_cast<const float4*>(W + (size_t)(kbeg + brow) * 1024 + n0 + bnc);
  for (int k0 = kbeg; k0 < kend; k0 += 16) {
    As[akc + 0][arow] = av.x; As[akc + 1][arow] = av.y;
    As[akc + 2][arow] = av.z; As[akc + 3][arow] = av.w;
    *reinterpret_cast<float4*>(&Bs[brow][bnc]) = bv;
    __syncthreads();
    float4 av2, bv2;
    if (k0 + 16 < kend) {
      av2 = *reinterpret_cast<const float4*>(A + (size_t)(m0 + arow) * 1024 + k0 + 16 + akc);
      bv2 = *reinterpret_cast<const float4*>(W + (size_t)(k0 + 16 + brow) * 1024 + n0 + bnc);
    }
    #pragma unroll
    for (int kk = 0; kk < 16; ++kk) {
      float4 a = *reinterpret_cast<const float4*>(&As[kk][ty * 4]);
      float4 b = *reinterpret_cast<const float4*>(&Bs[kk][tx * 4]);
      float aa[4] = {a.x, a.y, a.z, a.w};
      float bb[4] = {b.x, b.y, b.z, b.w};
      #pragma unroll
      for (int i = 0; i < 4; ++i)
        #pragma unroll
        for (int j = 0; j < 4; ++j)
          acc[i][j] = fmaf(aa[i], bb[j], acc[i][j]);
    }
    __syncthreads();
    av = av2; bv = bv2;
  }
  float* Co = Cp + (size_t)ks * 262144;
  #pragma unroll
  for (int i = 0; i < 4; ++i) {
    float4 w = make_float4(acc[i][0], acc[i][1], acc[i][2], acc[i][3]);
    *reinterpret_cast<float4*>(Co + (size_t)(m0 + ty * 4 + i) * 1024 + n0 + tx * 4) = w;
  }
}

// out = sum of 4 partials. grid = 1024.
__global__ __launch_bounds__(256) void o_reduce_kernel(const float* __restrict__ Op,
                                                       float* __restrict__ out) {
  int i = blockIdx.x * 256 + threadIdx.x;     // 262144
  out[i] = Op[i] + Op[262144 + i] + Op[524288 + i] + Op[786432 + i];
}

// ---------------------------------------------------------------------------
extern "C" void kernel_launch(void* const* d_in, const int* in_sizes, int n_in,
                              void* d_out, int out_size, void* d_ws, size_t ws_size,
                              hipStream_t stream) {
  const float* X    = (const float*)d_in[0];   // hidden_states (1,256,1024)
  const float* cosp = (const float*)d_in[1];   // (1,256,64)
  const float* sinp = (const float*)d_in[2];   // (1,256,64)
  // d_in[3] attention_mask: causal, implemented analytically
  const float* Wq   = (const float*)d_in[4];   // (1024,1024)
  const float* Wk   = (const float*)d_in[5];   // (1024,512)
  const float* Wv   = (const float*)d_in[6];   // (1024,512)
  const float* Wo   = (const float*)d_in[7];   // (1024,1024)

  float* out  = (float*)d_out;                 // 262144
  float* pOut = out + 262144;                  // 1048576
  float* qki  = pOut + 1048576;                // 1024
  float* vi   = qki + 1024;                    // 1024
  float* oi   = vi + 1024;                     // 1024

  float* ws       = (float*)d_ws;
  float* QKV      = ws;                        // 524288  (s-major, 2048 cols: q|k|v)
  float* aw       = ws + 524288;               // 1048576
  float* P2       = ws + 1572864;              // 4096
  float* attn_out = ws + 1576960;              // 262144
  float* qkpart   = ws + 1839104;              // 131072
  float* scratch  = ws + 1970176;              // 2097152 (QKV partials x4; reused for O partials x4)

  hipLaunchKernelGGL(gemm_qkv_kernel, dim3(512), dim3(256), 0, stream, X, Wq, Wk, Wv, scratch);
  hipLaunchKernelGGL(rope_reduce_kernel, dim3(1280), dim3(256), 0, stream, scratch, QKV, cosp, sinp);
  hipLaunchKernelGGL(qkaw_kernel, dim3(160), dim3(256), 0, stream, QKV, aw);
  hipLaunchKernelGGL(softmax_kernel, dim3(1024), dim3(256), 0, stream, aw, pOut, P2);
  hipLaunchKernelGGL(pdiff_kernel, dim3(512), dim3(256), 0, stream, QKV, aw, pOut, P2, qkpart);
  hipLaunchKernelGGL(attnv_kernel, dim3(512), dim3(256), 0, stream, QKV, pOut, attn_out);
  hipLaunchKernelGGL(qkred_kernel, dim3(4), dim3(256), 0, stream, qkpart, qki);
  hipLaunchKernelGGL(vimp_kernel, dim3(4), dim3(256), 0, stream, attn_out, vi, oi);
  hipLaunchKernelGGL(gemm_o_kernel, dim3(256), dim3(256), 0, stream, attn_out, Wo, scratch);
  hipLaunchKernelGGL(o_reduce_kernel, dim3(1024), dim3(256), 0, stream, scratch, out);
}

// Round 6
// 68.625 us; speedup vs baseline: 1.6760x; 1.3059x over previous
//
#include <hip/hip_runtime.h>
#include <math.h>

// Problem constants: B=1, S=256, HID=1024, H=16, KV=8, D=64, N_REP=2
#define SCALE 0.125f   // 1/sqrt(64)

typedef short short8 __attribute__((ext_vector_type(8)));
typedef float floatx4 __attribute__((ext_vector_type(4)));

static __device__ __forceinline__ ushort f2bf(float x) {
  uint32_t b = __float_as_uint(x);
  uint32_t r = (b + 0x7FFFu + ((b >> 16) & 1u)) >> 16;   // RNE
  return (ushort)r;
}

// ---------------------------------------------------------------------------
// MFMA bf16 GEMM 1: X(256x1024) @ [Wq|Wk|Wv](1024x2048) -> QKV partials.
// K-split 2. 64x64 tile, 4 waves (2x2), each wave 32x32 via 2x2 mfma 16x16x32.
// LDS: As[64][64] row-major bf16 (A[m][k]), Bs[64][64] (B^T: [n][k]), both
// XOR-swizzled: byte ^= ((row&7)<<4). Register-staged prefetch of next K64.
// grid = 256 (2 ksplit * 128 tiles), block = 256.
// ---------------------------------------------------------------------------
__global__ __launch_bounds__(256) void gemm_qkv_kernel(
    const float* __restrict__ X, const float* __restrict__ Wq,
    const float* __restrict__ Wk, const float* __restrict__ Wv,
    float* __restrict__ Cp) {
  __shared__ ushort As[4096];
  __shared__ ushort Bs[4096];
  char* Asc = (char*)As;
  char* Bsc = (char*)Bs;
  const int bx = blockIdx.x;
  const int ks = bx >> 7;            // 0..1
  const int tile = bx & 127;         // 4 m-tiles x 32 n-tiles
  const int tile_n = tile & 31, tile_m = tile >> 5;
  const int n0 = tile_n * 64, m0 = tile_m * 64;
  const float* Bp; int ldb, bc0;
  if (n0 < 1024)      { Bp = Wq; ldb = 1024; bc0 = n0; }
  else if (n0 < 1536) { Bp = Wk; ldb = 512;  bc0 = n0 - 1024; }
  else                { Bp = Wv; ldb = 512;  bc0 = n0 - 1536; }
  const int t = threadIdx.x;
  const int arow = t >> 4, acg = t & 15;   // A stage: rows arow+16i, cols acg*4
  const int bng = t & 15;                  // B stage: kpair (t>>4)+16i, n bng*4+j
  const int kbeg = ks * 512;
  float4 ra[4], rb0[2], rb1[2];
  auto LOAD = [&](int k0) {
    #pragma unroll
    for (int i = 0; i < 4; ++i)
      ra[i] = *reinterpret_cast<const float4*>(X + (size_t)(m0 + arow + 16 * i) * 1024 + k0 + acg * 4);
    #pragma unroll
    for (int i = 0; i < 2; ++i) {
      int k = 2 * ((t >> 4) + 16 * i);
      rb0[i] = *reinterpret_cast<const float4*>(Bp + (size_t)(k0 + k) * ldb + bc0 + bng * 4);
      rb1[i] = *reinterpret_cast<const float4*>(Bp + (size_t)(k0 + k + 1) * ldb + bc0 + bng * 4);
    }
  };
  LOAD(kbeg);
  const int wid = t >> 6, wr = wid >> 1, wc = wid & 1, lane = t & 63;
  const int lr = lane & 15, lk = lane >> 4;
  const int sw = (lr & 7) << 4;
  floatx4 acc[2][2];
  #pragma unroll
  for (int mt = 0; mt < 2; ++mt)
    #pragma unroll
    for (int nt = 0; nt < 2; ++nt)
      acc[mt][nt] = (floatx4){0.f, 0.f, 0.f, 0.f};
  for (int kt = 0; kt < 8; ++kt) {
    #pragma unroll
    for (int i = 0; i < 4; ++i) {
      int row = arow + 16 * i;
      ushort4 w;
      w.x = f2bf(ra[i].x); w.y = f2bf(ra[i].y); w.z = f2bf(ra[i].z); w.w = f2bf(ra[i].w);
      *reinterpret_cast<ushort4*>(Asc + row * 128 + ((acg * 8) ^ ((row & 7) << 4))) = w;
    }
    #pragma unroll
    for (int i = 0; i < 2; ++i) {
      int k = 2 * ((t >> 4) + 16 * i);
      const float* p0 = (const float*)&rb0[i];
      const float* p1 = (const float*)&rb1[i];
      #pragma unroll
      for (int j = 0; j < 4; ++j) {
        int n = bng * 4 + j;
        uint32_t v = (uint32_t)f2bf(p0[j]) | ((uint32_t)f2bf(p1[j]) << 16);
        *reinterpret_cast<uint32_t*>(Bsc + n * 128 + ((k * 2) ^ ((n & 7) << 4))) = v;
      }
    }
    __syncthreads();
    if (kt + 1 < 8) LOAD(kbeg + 64 * (kt + 1));
    #pragma unroll
    for (int kc = 0; kc < 2; ++kc) {
      short8 af[2], bf[2];
      #pragma unroll
      for (int mt = 0; mt < 2; ++mt)
        af[mt] = *reinterpret_cast<const short8*>(
            Asc + (wr * 32 + mt * 16 + lr) * 128 + ((kc * 64 + lk * 16) ^ sw));
      #pragma unroll
      for (int nt = 0; nt < 2; ++nt)
        bf[nt] = *reinterpret_cast<const short8*>(
            Bsc + (wc * 32 + nt * 16 + lr) * 128 + ((kc * 64 + lk * 16) ^ sw));
      #pragma unroll
      for (int mt = 0; mt < 2; ++mt)
        #pragma unroll
        for (int nt = 0; nt < 2; ++nt)
          acc[mt][nt] = __builtin_amdgcn_mfma_f32_16x16x32_bf16(af[mt], bf[nt], acc[mt][nt], 0, 0, 0);
    }
    __syncthreads();
  }
  float* Co = Cp + (size_t)ks * 524288;
  #pragma unroll
  for (int mt = 0; mt < 2; ++mt)
    #pragma unroll
    for (int nt = 0; nt < 2; ++nt)
      #pragma unroll
      for (int r = 0; r < 4; ++r) {
        int row = wr * 32 + mt * 16 + lk * 4 + r;
        int col = wc * 32 + nt * 16 + lr;
        Co[(size_t)(m0 + row) * 2048 + n0 + col] = acc[mt][nt][r];
      }
}

// ---------------------------------------------------------------------------
// Reduce the 2 QKV partials + apply RoPE to q (cols 0..1023) and k (1024..1535).
// v cols (1536..2047) just summed. grid = 1280, block = 256.
// ---------------------------------------------------------------------------
__global__ __launch_bounds__(256) void rope_reduce_kernel(
    const float* __restrict__ Cp, float* __restrict__ QKV,
    const float* __restrict__ cs, const float* __restrict__ sn) {
  int idx = blockIdx.x * 256 + threadIdx.x;
  const float* P0 = Cp;
  const float* P1 = Cp + 524288;
  if (idx < 196608) {                 // 256 s * 24 heads * 32 pairs
    int dp = idx & 31;
    int head = (idx >> 5) % 24;       // 0..15 q heads, 16..23 k heads
    int s = idx / 768;
    int base = s * 2048 + head * 64;
    int a1 = base + dp, a2 = base + dp + 32;
    float x1 = P0[a1] + P1[a1];
    float x2 = P0[a2] + P1[a2];
    float c1 = cs[s * 64 + dp],      s1v = sn[s * 64 + dp];
    float c2 = cs[s * 64 + dp + 32], s2v = sn[s * 64 + dp + 32];
    QKV[a1] = x1 * c1 - x2 * s1v;   // q' = q*cos + rot_half(q)*sin
    QKV[a2] = x2 * c2 + x1 * s2v;
  } else {
    int i2 = idx - 196608;            // 131072 v elements
    int s = i2 >> 9, c = 1536 + (i2 & 511);
    int a = s * 2048 + c;
    QKV[a] = P0[a] + P1[a];
  }
}

// ---------------------------------------------------------------------------
// attn_weights (pre-softmax, scale applied, causal region only).
// k-major LDS (stride 68 keeps float4 16B-aligned) -> ds_read_b128 fragments.
// grid = 160 (16 h * 10 lower-tri tiles), block = 256.
// ---------------------------------------------------------------------------
__global__ __launch_bounds__(256, 2) void qkaw_kernel(const float* __restrict__ QKV,
                                                      float* __restrict__ aw) {
  __shared__ float Qs[64][68];   // Qs[d][m]
  __shared__ float Ks[64][68];   // Ks[d][n]
  int h = blockIdx.x / 10;
  int tri = blockIdx.x % 10;
  int si = (tri >= 6) ? 3 : ((tri >= 3) ? 2 : ((tri >= 1) ? 1 : 0));
  int ti = tri - ((si * (si + 1)) >> 1);
  int s0 = si * 64, t0 = ti * 64;
  int g = h >> 1;
  int t = threadIdx.x;
  #pragma unroll
  for (int i = 0; i < 4; ++i) {
    int fi = t + i * 256;             // 1024 float4 slots -> 64x64 tile
    int row = fi >> 4, c = (fi & 15) * 4;
    float4 qv = *reinterpret_cast<const float4*>(QKV + (size_t)(s0 + row) * 2048 + h * 64 + c);
    Qs[c + 0][row] = qv.x; Qs[c + 1][row] = qv.y;
    Qs[c + 2][row] = qv.z; Qs[c + 3][row] = qv.w;
    float4 kv = *reinterpret_cast<const float4*>(QKV + (size_t)(t0 + row) * 2048 + 1024 + g * 64 + c);
    Ks[c + 0][row] = kv.x; Ks[c + 1][row] = kv.y;
    Ks[c + 2][row] = kv.z; Ks[c + 3][row] = kv.w;
  }
  __syncthreads();
  int ty = t >> 4, tx = t & 15;
  float acc[4][4] = {};
  #pragma unroll 8
  for (int kk = 0; kk < 64; ++kk) {
    float4 a = *reinterpret_cast<const float4*>(&Qs[kk][ty * 4]);
    float4 b = *reinterpret_cast<const float4*>(&Ks[kk][tx * 4]);
    float aa[4] = {a.x, a.y, a.z, a.w};
    float bb[4] = {b.x, b.y, b.z, b.w};
    #pragma unroll
    for (int i = 0; i < 4; ++i)
      #pragma unroll
      for (int j = 0; j < 4; ++j)
        acc[i][j] = fmaf(aa[i], bb[j], acc[i][j]);
  }
  for (int i = 0; i < 4; ++i) {
    int s = s0 + ty * 4 + i;
    for (int j = 0; j < 4; ++j) {
      int tt = t0 + tx * 4 + j;
      if (tt <= s) aw[((size_t)h * 256 + s) * 256 + tt] = acc[i][j] * SCALE;
    }
  }
}

// ---------------------------------------------------------------------------
// p = softmax(aw) per row; writes zeros for t>s; also P2[h,s] = sum_t p^2.
// one wave per row. grid = 1024, block = 256 (4 waves).
// ---------------------------------------------------------------------------
__global__ __launch_bounds__(256) void softmax_kernel(const float* __restrict__ aw,
    float* __restrict__ pOut, float* __restrict__ P2) {
  int wid = blockIdx.x * 4 + (threadIdx.x >> 6);   // row id 0..4095 (h*256+s)
  int lane = threadIdx.x & 63;
  int s = wid & 255;
  const float* row = aw + (size_t)wid * 256;
  float v[4], m = -3.0e38f;
  #pragma unroll
  for (int i = 0; i < 4; ++i) {
    int tt = lane + i * 64;
    v[i] = (tt <= s) ? row[tt] : -3.0e38f;
    m = fmaxf(m, v[i]);
  }
  #pragma unroll
  for (int off = 32; off; off >>= 1) m = fmaxf(m, __shfl_xor(m, off));
  float e[4], sum = 0.f;
  #pragma unroll
  for (int i = 0; i < 4; ++i) {
    int tt = lane + i * 64;
    e[i] = (tt <= s) ? __expf(v[i] - m) : 0.f;
    sum += e[i];
  }
  #pragma unroll
  for (int off = 32; off; off >>= 1) sum += __shfl_xor(sum, off);
  float inv = 1.f / sum;
  float p2 = 0.f;
  #pragma unroll
  for (int i = 0; i < 4; ++i) {
    float pv = e[i] * inv;
    pOut[(size_t)wid * 256 + lane + i * 64] = pv;
    p2 = fmaf(pv, pv, p2);
  }
  #pragma unroll
  for (int off = 32; off; off >>= 1) p2 += __shfl_xor(p2, off);
  if (lane == 0) P2[wid] = p2;
}

// ---------------------------------------------------------------------------
// The fused p_diff / qk_importance kernel.
// For each (h,s,d): z_t = scale*aw[t] - (scale*q_d)*k[t,d];
//   sum_t(p_diff-p)^2 = S2/S1^2 - 2*S3/S1 + sum_t p^2,
//   S1=sum e^z, S2=sum e^{2z}, S3=sum e^z p_t.  (|z|<~3 -> no max needed.)
// wave = one (h,row-pair); lane = d. K-head staged in LDS. Rows paired
// (j, 255-j) for triangular balance. grid = 512 (8 g * 64 u), block = 256.
// ---------------------------------------------------------------------------
__global__ __launch_bounds__(256) void pdiff_kernel(
    const float* __restrict__ QKV, const float* __restrict__ aw,
    const float* __restrict__ p, const float* __restrict__ P2,
    float* __restrict__ qkpart) {
  __shared__ float ksh[256 * 64];      // 64 KB: k[g][t][d]
  __shared__ float2 rb[4][2][256];     // 16 KB: per wave, per row: (scale*aw_t, p_t)
  int g = blockIdx.x >> 6;
  int u = blockIdx.x & 63;
  int t = threadIdx.x;
  #pragma unroll
  for (int i = 0; i < 16; ++i) {
    int fi = t + i * 256;              // 4096 float4 slots
    int tt = fi >> 4, c = (fi & 15) * 4;
    float4 kv = *reinterpret_cast<const float4*>(QKV + (size_t)tt * 2048 + 1024 + g * 64 + c);
    *reinterpret_cast<float4*>(&ksh[tt * 64 + c]) = kv;
  }
  int w = t >> 6, lane = t & 63;
  int h = 2 * g + (w & 1);
  int j = 2 * u + (w >> 1);
  for (int r = 0; r < 2; ++r) {
    int s = r ? 255 - j : j;
    const float* awRow = aw + ((size_t)h * 256 + s) * 256;
    const float* pRow  = p  + ((size_t)h * 256 + s) * 256;
    #pragma unroll
    for (int i = 0; i < 4; ++i) {
      int idx = lane + i * 64;
      rb[w][r][idx] = make_float2(awRow[idx] * SCALE, pRow[idx]);
    }
  }
  __syncthreads();
  float acc = 0.f;
  for (int r = 0; r < 2; ++r) {
    int s = r ? 255 - j : j;
    float cd = SCALE * QKV[(size_t)s * 2048 + h * 64 + lane];
    float S1 = 0.f, S2 = 0.f, S3 = 0.f;
    const float2* rbr = rb[w][r];
    for (int tt = 0; tt <= s; ++tt) {
      float kv = ksh[tt * 64 + lane];
      float2 ap = rbr[tt];
      float z = fmaf(-cd, kv, ap.x);
      float e = __expf(z);
      S1 += e;
      S2 = fmaf(e, e, S2);
      S3 = fmaf(e, ap.y, S3);
    }
    float inv = 1.f / S1;
    acc += S2 * inv * inv - 2.f * S3 * inv + P2[h * 256 + s];
  }
  qkpart[((size_t)h * 128 + j) * 64 + lane] = acc;
}

// ---------------------------------------------------------------------------
// attn_out[s][h*64+d] = sum_t p[h,s,t] * v[g,t,d].  Same wave layout as pdiff,
// v-head staged in LDS. grid = 512, block = 256.
// ---------------------------------------------------------------------------
__global__ __launch_bounds__(256) void attnv_kernel(
    const float* __restrict__ QKV, const float* __restrict__ p,
    float* __restrict__ attn_out) {
  __shared__ float vsh[256 * 64];
  int g = blockIdx.x >> 6;
  int u = blockIdx.x & 63;
  int t = threadIdx.x;
  #pragma unroll
  for (int i = 0; i < 16; ++i) {
    int fi = t + i * 256;
    int tt = fi >> 4, c = (fi & 15) * 4;
    float4 vv = *reinterpret_cast<const float4*>(QKV + (size_t)tt * 2048 + 1536 + g * 64 + c);
    *reinterpret_cast<float4*>(&vsh[tt * 64 + c]) = vv;
  }
  __syncthreads();
  int w = t >> 6, lane = t & 63;
  int h = 2 * g + (w & 1);
  int j = 2 * u + (w >> 1);
  for (int r = 0; r < 2; ++r) {
    int s = r ? 255 - j : j;
    const float* pRow = p + ((size_t)h * 256 + s) * 256;
    float acc = 0.f;
    for (int tt = 0; tt <= s; ++tt)
      acc = fmaf(pRow[tt], vsh[tt * 64 + lane], acc);
    attn_out[(size_t)s * 1024 + h * 64 + lane] = acc;
  }
}

// ---------------------------------------------------------------------------
// Tail reductions merged: blocks 0..3 -> qk_importance, 4..7 -> v/o_importance.
// grid = 8, block = 256.
// ---------------------------------------------------------------------------
__global__ __launch_bounds__(256) void tail_red_kernel(
    const float* __restrict__ qkpart, const float* __restrict__ attn_out,
    float* __restrict__ qkout, float* __restrict__ vout, float* __restrict__ oout) {
  int t = threadIdx.x;
  if (blockIdx.x < 4) {
    int idx = blockIdx.x * 256 + t;    // 1024 = h*64+d
    int h = idx >> 6, d = idx & 63;
    float sum = 0.f;
    for (int j = 0; j < 128; ++j) sum += qkpart[((size_t)h * 128 + j) * 64 + d];
    qkout[idx] = sum;
  } else {
    int c = (blockIdx.x - 4) * 256 + t; // 1024
    float sum = 0.f;
    for (int s = 0; s < 256; ++s) sum += fabsf(attn_out[(size_t)s * 1024 + c]);
    vout[c] = sum;
    oout[c] = sum;
  }
}

// ---------------------------------------------------------------------------
// MFMA bf16 GEMM 2: attn_out(256x1024) @ Wo(1024x1024) -> out partials.
// K-split 4, same structure as gemm_qkv. grid = 256 (4 ks * 64 tiles).
// ---------------------------------------------------------------------------
__global__ __launch_bounds__(256) void gemm_o_kernel(
    const float* __restrict__ A, const float* __restrict__ W,
    float* __restrict__ Cp) {
  __shared__ ushort As[4096];
  __shared__ ushort Bs[4096];
  char* Asc = (char*)As;
  char* Bsc = (char*)Bs;
  const int bx = blockIdx.x;
  const int ks = bx >> 6;            // 0..3
  const int tile = bx & 63;          // 4 m-tiles x 16 n-tiles
  const int tile_n = tile & 15, tile_m = tile >> 4;
  const int n0 = tile_n * 64, m0 = tile_m * 64;
  const int t = threadIdx.x;
  const int arow = t >> 4, acg = t & 15;
  const int bng = t & 15;
  const int kbeg = ks * 256;
  float4 ra[4], rb0[2], rb1[2];
  auto LOAD = [&](int k0) {
    #pragma unroll
    for (int i = 0; i < 4; ++i)
      ra[i] = *reinterpret_cast<const float4*>(A + (size_t)(m0 + arow + 16 * i) * 1024 + k0 + acg * 4);
    #pragma unroll
    for (int i = 0; i < 2; ++i) {
      int k = 2 * ((t >> 4) + 16 * i);
      rb0[i] = *reinterpret_cast<const float4*>(W + (size_t)(k0 + k) * 1024 + n0 + bng * 4);
      rb1[i] = *reinterpret_cast<const float4*>(W + (size_t)(k0 + k + 1) * 1024 + n0 + bng * 4);
    }
  };
  LOAD(kbeg);
  const int wid = t >> 6, wr = wid >> 1, wc = wid & 1, lane = t & 63;
  const int lr = lane & 15, lk = lane >> 4;
  const int sw = (lr & 7) << 4;
  floatx4 acc[2][2];
  #pragma unroll
  for (int mt = 0; mt < 2; ++mt)
    #pragma unroll
    for (int nt = 0; nt < 2; ++nt)
      acc[mt][nt] = (floatx4){0.f, 0.f, 0.f, 0.f};
  for (int kt = 0; kt < 4; ++kt) {
    #pragma unroll
    for (int i = 0; i < 4; ++i) {
      int row = arow + 16 * i;
      ushort4 w;
      w.x = f2bf(ra[i].x); w.y = f2bf(ra[i].y); w.z = f2bf(ra[i].z); w.w = f2bf(ra[i].w);
      *reinterpret_cast<ushort4*>(Asc + row * 128 + ((acg * 8) ^ ((row & 7) << 4))) = w;
    }
    #pragma unroll
    for (int i = 0; i < 2; ++i) {
      int k = 2 * ((t >> 4) + 16 * i);
      const float* p0 = (const float*)&rb0[i];
      const float* p1 = (const float*)&rb1[i];
      #pragma unroll
      for (int j = 0; j < 4; ++j) {
        int n = bng * 4 + j;
        uint32_t v = (uint32_t)f2bf(p0[j]) | ((uint32_t)f2bf(p1[j]) << 16);
        *reinterpret_cast<uint32_t*>(Bsc + n * 128 + ((k * 2) ^ ((n & 7) << 4))) = v;
      }
    }
    __syncthreads();
    if (kt + 1 < 4) LOAD(kbeg + 64 * (kt + 1));
    #pragma unroll
    for (int kc = 0; kc < 2; ++kc) {
      short8 af[2], bf[2];
      #pragma unroll
      for (int mt = 0; mt < 2; ++mt)
        af[mt] = *reinterpret_cast<const short8*>(
            Asc + (wr * 32 + mt * 16 + lr) * 128 + ((kc * 64 + lk * 16) ^ sw));
      #pragma unroll
      for (int nt = 0; nt < 2; ++nt)
        bf[nt] = *reinterpret_cast<const short8*>(
            Bsc + (wc * 32 + nt * 16 + lr) * 128 + ((kc * 64 + lk * 16) ^ sw));
      #pragma unroll
      for (int mt = 0; mt < 2; ++mt)
        #pragma unroll
        for (int nt = 0; nt < 2; ++nt)
          acc[mt][nt] = __builtin_amdgcn_mfma_f32_16x16x32_bf16(af[mt], bf[nt], acc[mt][nt], 0, 0, 0);
    }
    __syncthreads();
  }
  float* Co = Cp + (size_t)ks * 262144;
  #pragma unroll
  for (int mt = 0; mt < 2; ++mt)
    #pragma unroll
    for (int nt = 0; nt < 2; ++nt)
      #pragma unroll
      for (int r = 0; r < 4; ++r) {
        int row = wr * 32 + mt * 16 + lk * 4 + r;
        int col = wc * 32 + nt * 16 + lr;
        Co[(size_t)(m0 + row) * 1024 + n0 + col] = acc[mt][nt][r];
      }
}

// out = sum of 4 partials. grid = 1024.
__global__ __launch_bounds__(256) void o_reduce_kernel(const float* __restrict__ Op,
                                                       float* __restrict__ out) {
  int i = blockIdx.x * 256 + threadIdx.x;     // 262144
  out[i] = Op[i] + Op[262144 + i] + Op[524288 + i] + Op[786432 + i];
}

// ---------------------------------------------------------------------------
extern "C" void kernel_launch(void* const* d_in, const int* in_sizes, int n_in,
                              void* d_out, int out_size, void* d_ws, size_t ws_size,
                              hipStream_t stream) {
  const float* X    = (const float*)d_in[0];   // hidden_states (1,256,1024)
  const float* cosp = (const float*)d_in[1];   // (1,256,64)
  const float* sinp = (const float*)d_in[2];   // (1,256,64)
  // d_in[3] attention_mask: causal, implemented analytically
  const float* Wq   = (const float*)d_in[4];   // (1024,1024)
  const float* Wk   = (const float*)d_in[5];   // (1024,512)
  const float* Wv   = (const float*)d_in[6];   // (1024,512)
  const float* Wo   = (const float*)d_in[7];   // (1024,1024)

  float* out  = (float*)d_out;                 // 262144
  float* pOut = out + 262144;                  // 1048576
  float* qki  = pOut + 1048576;                // 1024
  float* vi   = qki + 1024;                    // 1024
  float* oi   = vi + 1024;                     // 1024

  float* ws       = (float*)d_ws;
  float* QKV      = ws;                        // 524288  (s-major, 2048 cols: q|k|v)
  float* aw       = ws + 524288;               // 1048576
  float* P2       = ws + 1572864;              // 4096
  float* attn_out = ws + 1576960;              // 262144
  float* qkpart   = ws + 1839104;              // 131072
  float* scratch  = ws + 1970176;              // 1048576 (QKV partials x2; O partials x4)

  hipLaunchKernelGGL(gemm_qkv_kernel, dim3(256), dim3(256), 0, stream, X, Wq, Wk, Wv, scratch);
  hipLaunchKernelGGL(rope_reduce_kernel, dim3(1280), dim3(256), 0, stream, scratch, QKV, cosp, sinp);
  hipLaunchKernelGGL(qkaw_kernel, dim3(160), dim3(256), 0, stream, QKV, aw);
  hipLaunchKernelGGL(softmax_kernel, dim3(1024), dim3(256), 0, stream, aw, pOut, P2);
  hipLaunchKernelGGL(pdiff_kernel, dim3(512), dim3(256), 0, stream, QKV, aw, pOut, P2, qkpart);
  hipLaunchKernelGGL(attnv_kernel, dim3(512), dim3(256), 0, stream, QKV, pOut, attn_out);
  hipLaunchKernelGGL(tail_red_kernel, dim3(8), dim3(256), 0, stream, qkpart, attn_out, qki, vi, oi);
  hipLaunchKernelGGL(gemm_o_kernel, dim3(256), dim3(256), 0, stream, attn_out, Wo, scratch);
  hipLaunchKernelGGL(o_reduce_kernel, dim3(1024), dim3(256), 0, stream, scratch, out);
}

// Round 7
// 57.547 us; speedup vs baseline: 1.9986x; 1.1925x over previous
//
#include <hip/hip_runtime.h>
#include <math.h>

// Problem constants: B=1, S=256, HID=1024, H=16, KV=8, D=64, N_REP=2
#define SCALE 0.125f   // 1/sqrt(64)

typedef short short8 __attribute__((ext_vector_type(8)));
typedef float floatx4 __attribute__((ext_vector_type(4)));

static __device__ __forceinline__ ushort f2bf(float x) {
  uint32_t b = __float_as_uint(x);
  uint32_t r = (b + 0x7FFFu + ((b >> 16) & 1u)) >> 16;   // RNE
  return (ushort)r;
}
static __device__ __forceinline__ float bf2f(ushort u) {
  return __uint_as_float(((uint32_t)u) << 16);
}

// ---------------------------------------------------------------------------
// MFMA bf16 GEMM 1: X(256x1024) @ [Wq|Wk|Wv](1024x2048) -> QKV partials.
// K-split 2. 64x64 tile, 4 waves (2x2), each wave 32x32 via 2x2 mfma 16x16x32.
// grid = 256 (2 ksplit * 128 tiles), block = 256.  (verified R6)
// ---------------------------------------------------------------------------
__global__ __launch_bounds__(256) void gemm_qkv_kernel(
    const float* __restrict__ X, const float* __restrict__ Wq,
    const float* __restrict__ Wk, const float* __restrict__ Wv,
    float* __restrict__ Cp) {
  __shared__ ushort As[4096];
  __shared__ ushort Bs[4096];
  char* Asc = (char*)As;
  char* Bsc = (char*)Bs;
  const int bx = blockIdx.x;
  const int ks = bx >> 7;            // 0..1
  const int tile = bx & 127;         // 4 m-tiles x 32 n-tiles
  const int tile_n = tile & 31, tile_m = tile >> 5;
  const int n0 = tile_n * 64, m0 = tile_m * 64;
  const float* Bp; int ldb, bc0;
  if (n0 < 1024)      { Bp = Wq; ldb = 1024; bc0 = n0; }
  else if (n0 < 1536) { Bp = Wk; ldb = 512;  bc0 = n0 - 1024; }
  else                { Bp = Wv; ldb = 512;  bc0 = n0 - 1536; }
  const int t = threadIdx.x;
  const int arow = t >> 4, acg = t & 15;
  const int bng = t & 15;
  const int kbeg = ks * 512;
  float4 ra[4], rb0[2], rb1[2];
  auto LOAD = [&](int k0) {
    #pragma unroll
    for (int i = 0; i < 4; ++i)
      ra[i] = *reinterpret_cast<const float4*>(X + (size_t)(m0 + arow + 16 * i) * 1024 + k0 + acg * 4);
    #pragma unroll
    for (int i = 0; i < 2; ++i) {
      int k = 2 * ((t >> 4) + 16 * i);
      rb0[i] = *reinterpret_cast<const float4*>(Bp + (size_t)(k0 + k) * ldb + bc0 + bng * 4);
      rb1[i] = *reinterpret_cast<const float4*>(Bp + (size_t)(k0 + k + 1) * ldb + bc0 + bng * 4);
    }
  };
  LOAD(kbeg);
  const int wid = t >> 6, wr = wid >> 1, wc = wid & 1, lane = t & 63;
  const int lr = lane & 15, lk = lane >> 4;
  const int sw = (lr & 7) << 4;
  floatx4 acc[2][2];
  #pragma unroll
  for (int mt = 0; mt < 2; ++mt)
    #pragma unroll
    for (int nt = 0; nt < 2; ++nt)
      acc[mt][nt] = (floatx4){0.f, 0.f, 0.f, 0.f};
  for (int kt = 0; kt < 8; ++kt) {
    #pragma unroll
    for (int i = 0; i < 4; ++i) {
      int row = arow + 16 * i;
      ushort4 w;
      w.x = f2bf(ra[i].x); w.y = f2bf(ra[i].y); w.z = f2bf(ra[i].z); w.w = f2bf(ra[i].w);
      *reinterpret_cast<ushort4*>(Asc + row * 128 + ((acg * 8) ^ ((row & 7) << 4))) = w;
    }
    #pragma unroll
    for (int i = 0; i < 2; ++i) {
      int k = 2 * ((t >> 4) + 16 * i);
      const float* p0 = (const float*)&rb0[i];
      const float* p1 = (const float*)&rb1[i];
      #pragma unroll
      for (int j = 0; j < 4; ++j) {
        int n = bng * 4 + j;
        uint32_t v = (uint32_t)f2bf(p0[j]) | ((uint32_t)f2bf(p1[j]) << 16);
        *reinterpret_cast<uint32_t*>(Bsc + n * 128 + ((k * 2) ^ ((n & 7) << 4))) = v;
      }
    }
    __syncthreads();
    if (kt + 1 < 8) LOAD(kbeg + 64 * (kt + 1));
    #pragma unroll
    for (int kc = 0; kc < 2; ++kc) {
      short8 af[2], bf[2];
      #pragma unroll
      for (int mt = 0; mt < 2; ++mt)
        af[mt] = *reinterpret_cast<const short8*>(
            Asc + (wr * 32 + mt * 16 + lr) * 128 + ((kc * 64 + lk * 16) ^ sw));
      #pragma unroll
      for (int nt = 0; nt < 2; ++nt)
        bf[nt] = *reinterpret_cast<const short8*>(
            Bsc + (wc * 32 + nt * 16 + lr) * 128 + ((kc * 64 + lk * 16) ^ sw));
      #pragma unroll
      for (int mt = 0; mt < 2; ++mt)
        #pragma unroll
        for (int nt = 0; nt < 2; ++nt)
          acc[mt][nt] = __builtin_amdgcn_mfma_f32_16x16x32_bf16(af[mt], bf[nt], acc[mt][nt], 0, 0, 0);
    }
    __syncthreads();
  }
  float* Co = Cp + (size_t)ks * 524288;
  #pragma unroll
  for (int mt = 0; mt < 2; ++mt)
    #pragma unroll
    for (int nt = 0; nt < 2; ++nt)
      #pragma unroll
      for (int r = 0; r < 4; ++r) {
        int row = wr * 32 + mt * 16 + lk * 4 + r;
        int col = wc * 32 + nt * 16 + lr;
        Co[(size_t)(m0 + row) * 2048 + n0 + col] = acc[mt][nt][r];
      }
}

// ---------------------------------------------------------------------------
// Reduce the 2 QKV partials + RoPE on q/k heads. grid = 1280, block = 256.
// ---------------------------------------------------------------------------
__global__ __launch_bounds__(256) void rope_reduce_kernel(
    const float* __restrict__ Cp, float* __restrict__ QKV,
    const float* __restrict__ cs, const float* __restrict__ sn) {
  int idx = blockIdx.x * 256 + threadIdx.x;
  const float* P0 = Cp;
  const float* P1 = Cp + 524288;
  if (idx < 196608) {                 // 256 s * 24 heads * 32 pairs
    int dp = idx & 31;
    int head = (idx >> 5) % 24;       // 0..15 q heads, 16..23 k heads
    int s = idx / 768;
    int base = s * 2048 + head * 64;
    int a1 = base + dp, a2 = base + dp + 32;
    float x1 = P0[a1] + P1[a1];
    float x2 = P0[a2] + P1[a2];
    float c1 = cs[s * 64 + dp],      s1v = sn[s * 64 + dp];
    float c2 = cs[s * 64 + dp + 32], s2v = sn[s * 64 + dp + 32];
    QKV[a1] = x1 * c1 - x2 * s1v;   // q' = q*cos + rot_half(q)*sin
    QKV[a2] = x2 * c2 + x1 * s2v;
  } else {
    int i2 = idx - 196608;            // 131072 v elements
    int s = i2 >> 9, c = 1536 + (i2 & 511);
    int a = s * 2048 + c;
    QKV[a] = P0[a] + P1[a];
  }
}

// ---------------------------------------------------------------------------
// Fused QK^T + softmax. One WG per (h, 16-row strip j): rows 16j..16j+15,
// cols 0..16j+15 via bf16 MFMA (gemm-verified frag/swizzle pattern).
// Writes p (fp32, zeros beyond diag), P2 = sum p^2, aw2 = bf16(aw*scale).
// grid = 256 (h*16 + j), block = 256.
// ---------------------------------------------------------------------------
__global__ __launch_bounds__(256) void qk_sm_kernel(
    const float* __restrict__ QKV, float* __restrict__ pOut,
    ushort* __restrict__ aw2, float* __restrict__ P2) {
  __shared__ ushort ksh[16384];      // 32KB swizzled [t][d]
  __shared__ ushort qsh[1024];       // 2KB  swizzled [r][d]
  __shared__ float awsh[16][260];    // padded: conflict-free col reads
  char* kshc = (char*)ksh;
  char* qshc = (char*)qsh;
  const int h = blockIdx.x >> 4, j = blockIdx.x & 15;
  const int g = h >> 1;
  const int t = threadIdx.x;
  // stage k rows 0..16j+15 (bf16, gemm-style XOR swizzle)
  for (int i = 0; i <= j; ++i) {
    int row = (t >> 4) + 16 * i;
    int c = (t & 15) * 4;
    float4 kv = *reinterpret_cast<const float4*>(QKV + (size_t)row * 2048 + 1024 + g * 64 + c);
    ushort4 w;
    w.x = f2bf(kv.x); w.y = f2bf(kv.y); w.z = f2bf(kv.z); w.w = f2bf(kv.w);
    *reinterpret_cast<ushort4*>(kshc + row * 128 + ((c * 2) ^ ((row & 7) << 4))) = w;
  }
  { // stage q strip (16 rows)
    int row = t >> 4, c = (t & 15) * 4;
    float4 qv = *reinterpret_cast<const float4*>(QKV + (size_t)(16 * j + row) * 2048 + h * 64 + c);
    ushort4 w;
    w.x = f2bf(qv.x); w.y = f2bf(qv.y); w.z = f2bf(qv.z); w.w = f2bf(qv.w);
    *reinterpret_cast<ushort4*>(qshc + row * 128 + ((c * 2) ^ ((row & 7) << 4))) = w;
  }
  __syncthreads();
  const int w = t >> 6, lane = t & 63;
  const int lr = lane & 15, lk = lane >> 4;
  const int sw = (lr & 7) << 4;
  // MFMA: wave w handles n-tiles w, w+4, w+8, w+12 (those <= j)
  floatx4 acc[4];
  #pragma unroll
  for (int q4 = 0; q4 < 4; ++q4) acc[q4] = (floatx4){0.f, 0.f, 0.f, 0.f};
  #pragma unroll
  for (int q4 = 0; q4 < 4; ++q4) {
    int nt = w + 4 * q4;
    if (nt <= j) {
      #pragma unroll
      for (int kc = 0; kc < 2; ++kc) {
        short8 af = *reinterpret_cast<const short8*>(
            qshc + lr * 128 + ((kc * 64 + lk * 16) ^ sw));
        int tt = nt * 16 + lr;
        short8 bf = *reinterpret_cast<const short8*>(
            kshc + tt * 128 + ((kc * 64 + lk * 16) ^ ((tt & 7) << 4)));
        acc[q4] = __builtin_amdgcn_mfma_f32_16x16x32_bf16(af, bf, acc[q4], 0, 0, 0);
      }
    }
  }
  #pragma unroll
  for (int q4 = 0; q4 < 4; ++q4) {
    int nt = w + 4 * q4;
    if (nt <= j) {
      #pragma unroll
      for (int r = 0; r < 4; ++r)
        awsh[lk * 4 + r][nt * 16 + lr] = acc[q4][r];
    }
  }
  __syncthreads();
  // softmax: wave w -> rows 4w..4w+3 (s = 16j+row); lane covers 4 cols each
  for (int rr = 0; rr < 4; ++rr) {
    int row = 4 * w + rr;
    int s = 16 * j + row;
    float v[4], m = -3.0e38f;
    #pragma unroll
    for (int i = 0; i < 4; ++i) {
      int tc = lane + 64 * i;
      v[i] = (tc <= s) ? awsh[row][tc] * SCALE : -3.0e38f;
      m = fmaxf(m, v[i]);
    }
    #pragma unroll
    for (int off = 32; off; off >>= 1) m = fmaxf(m, __shfl_xor(m, off));
    float e[4], sum = 0.f;
    #pragma unroll
    for (int i = 0; i < 4; ++i) {
      int tc = lane + 64 * i;
      e[i] = (tc <= s) ? __expf(v[i] - m) : 0.f;
      sum += e[i];
    }
    #pragma unroll
    for (int off = 32; off; off >>= 1) sum += __shfl_xor(sum, off);
    float inv = 1.f / sum;
    float p2 = 0.f;
    size_t rowbase = ((size_t)h * 256 + s) * 256;
    #pragma unroll
    for (int i = 0; i < 4; ++i) {
      int tc = lane + 64 * i;
      float pv = e[i] * inv;
      pOut[rowbase + tc] = pv;
      p2 = fmaf(pv, pv, p2);
      if (tc <= s) aw2[rowbase + tc] = f2bf(v[i]);
    }
    #pragma unroll
    for (int off = 32; off; off >>= 1) p2 += __shfl_xor(p2, off);
    if (lane == 0) P2[h * 256 + s] = p2;
  }
}

// ---------------------------------------------------------------------------
// Merged p_diff + PV kernel. For each (h,s,d):
//   z_t = aw2[t] - (scale*q_d)*k[t,d];  S1=sum e^z, S2=sum e^2z, S3=sum e^z p_t
//   qk_importance partial = S2/S1^2 - 2*S3/S1 + sum p^2;  AV = sum p_t v[t,d].
// k,v staged bf16 in LDS (linear [t][d]); rb holds (aw2_t, p_t) broadcast.
// wave = (h, row-pair j/255-j). grid = 512 (8 g * 64 u), block = 256.
// ---------------------------------------------------------------------------
__global__ __launch_bounds__(256) void pdiff_attnv_kernel(
    const float* __restrict__ QKV, const ushort* __restrict__ aw2,
    const float* __restrict__ p, const float* __restrict__ P2,
    float* __restrict__ qkpart, float* __restrict__ attn_out) {
  __shared__ ushort ksh[16384];        // 32KB linear [t][d] bf16
  __shared__ ushort vsh[16384];        // 32KB linear [t][d] bf16
  __shared__ float2 rb[4][2][256];     // 16KB (aw2_t, p_t) per wave-row
  int g = blockIdx.x >> 6;
  int u = blockIdx.x & 63;
  int t = threadIdx.x;
  #pragma unroll
  for (int i = 0; i < 16; ++i) {
    int fi = t + i * 256;              // 4096 float4 slots
    int tt = fi >> 4, c = (fi & 15) * 4;
    float4 kv = *reinterpret_cast<const float4*>(QKV + (size_t)tt * 2048 + 1024 + g * 64 + c);
    float4 vv = *reinterpret_cast<const float4*>(QKV + (size_t)tt * 2048 + 1536 + g * 64 + c);
    ushort4 wk, wv;
    wk.x = f2bf(kv.x); wk.y = f2bf(kv.y); wk.z = f2bf(kv.z); wk.w = f2bf(kv.w);
    wv.x = f2bf(vv.x); wv.y = f2bf(vv.y); wv.z = f2bf(vv.z); wv.w = f2bf(vv.w);
    *reinterpret_cast<ushort4*>(&ksh[tt * 64 + c]) = wk;
    *reinterpret_cast<ushort4*>(&vsh[tt * 64 + c]) = wv;
  }
  int w = t >> 6, lane = t & 63;
  int h = 2 * g + (w & 1);
  int jj = 2 * u + (w >> 1);
  for (int r = 0; r < 2; ++r) {
    int s = r ? 255 - jj : jj;
    size_t rowbase = ((size_t)h * 256 + s) * 256;
    #pragma unroll
    for (int i = 0; i < 4; ++i) {
      int idx = lane + i * 64;
      rb[w][r][idx] = make_float2(bf2f(aw2[rowbase + idx]), p[rowbase + idx]);
    }
  }
  __syncthreads();
  float qk_acc = 0.f;
  for (int r = 0; r < 2; ++r) {
    int s = r ? 255 - jj : jj;
    float cd = SCALE * QKV[(size_t)s * 2048 + h * 64 + lane];
    float S1 = 0.f, S2 = 0.f, S3 = 0.f, AV = 0.f;
    const float2* rbr = rb[w][r];
    for (int tt = 0; tt <= s; ++tt) {
      float kf = bf2f(ksh[tt * 64 + lane]);
      float vf = bf2f(vsh[tt * 64 + lane]);
      float2 ap = rbr[tt];
      float z = fmaf(-cd, kf, ap.x);
      float e = __expf(z);
      S1 += e;
      S2 = fmaf(e, e, S2);
      S3 = fmaf(e, ap.y, S3);
      AV = fmaf(ap.y, vf, AV);
    }
    float inv = 1.f / S1;
    qk_acc += S2 * inv * inv - 2.f * S3 * inv + P2[h * 256 + s];
    attn_out[(size_t)s * 1024 + h * 64 + lane] = AV;
  }
  qkpart[((size_t)h * 128 + jj) * 64 + lane] = qk_acc;
}

// ---------------------------------------------------------------------------
// MFMA bf16 GEMM 2: attn_out(256x1024) @ Wo(1024x1024) -> out partials.
// K-split 4. grid = 256.  (verified R6)
// ---------------------------------------------------------------------------
__global__ __launch_bounds__(256) void gemm_o_kernel(
    const float* __restrict__ A, const float* __restrict__ W,
    float* __restrict__ Cp) {
  __shared__ ushort As[4096];
  __shared__ ushort Bs[4096];
  char* Asc = (char*)As;
  char* Bsc = (char*)Bs;
  const int bx = blockIdx.x;
  const int ks = bx >> 6;            // 0..3
  const int tile = bx & 63;          // 4 m-tiles x 16 n-tiles
  const int tile_n = tile & 15, tile_m = tile >> 4;
  const int n0 = tile_n * 64, m0 = tile_m * 64;
  const int t = threadIdx.x;
  const int arow = t >> 4, acg = t & 15;
  const int bng = t & 15;
  const int kbeg = ks * 256;
  float4 ra[4], rb0[2], rb1[2];
  auto LOAD = [&](int k0) {
    #pragma unroll
    for (int i = 0; i < 4; ++i)
      ra[i] = *reinterpret_cast<const float4*>(A + (size_t)(m0 + arow + 16 * i) * 1024 + k0 + acg * 4);
    #pragma unroll
    for (int i = 0; i < 2; ++i) {
      int k = 2 * ((t >> 4) + 16 * i);
      rb0[i] = *reinterpret_cast<const float4*>(W + (size_t)(k0 + k) * 1024 + n0 + bng * 4);
      rb1[i] = *reinterpret_cast<const float4*>(W + (size_t)(k0 + k + 1) * 1024 + n0 + bng * 4);
    }
  };
  LOAD(kbeg);
  const int wid = t >> 6, wr = wid >> 1, wc = wid & 1, lane = t & 63;
  const int lr = lane & 15, lk = lane >> 4;
  const int sw = (lr & 7) << 4;
  floatx4 acc[2][2];
  #pragma unroll
  for (int mt = 0; mt < 2; ++mt)
    #pragma unroll
    for (int nt = 0; nt < 2; ++nt)
      acc[mt][nt] = (floatx4){0.f, 0.f, 0.f, 0.f};
  for (int kt = 0; kt < 4; ++kt) {
    #pragma unroll
    for (int i = 0; i < 4; ++i) {
      int row = arow + 16 * i;
      ushort4 w;
      w.x = f2bf(ra[i].x); w.y = f2bf(ra[i].y); w.z = f2bf(ra[i].z); w.w = f2bf(ra[i].w);
      *reinterpret_cast<ushort4*>(Asc + row * 128 + ((acg * 8) ^ ((row & 7) << 4))) = w;
    }
    #pragma unroll
    for (int i = 0; i < 2; ++i) {
      int k = 2 * ((t >> 4) + 16 * i);
      const float* p0 = (const float*)&rb0[i];
      const float* p1 = (const float*)&rb1[i];
      #pragma unroll
      for (int j = 0; j < 4; ++j) {
        int n = bng * 4 + j;
        uint32_t v = (uint32_t)f2bf(p0[j]) | ((uint32_t)f2bf(p1[j]) << 16);
        *reinterpret_cast<uint32_t*>(Bsc + n * 128 + ((k * 2) ^ ((n & 7) << 4))) = v;
      }
    }
    __syncthreads();
    if (kt + 1 < 4) LOAD(kbeg + 64 * (kt + 1));
    #pragma unroll
    for (int kc = 0; kc < 2; ++kc) {
      short8 af[2], bf[2];
      #pragma unroll
      for (int mt = 0; mt < 2; ++mt)
        af[mt] = *reinterpret_cast<const short8*>(
            Asc + (wr * 32 + mt * 16 + lr) * 128 + ((kc * 64 + lk * 16) ^ sw));
      #pragma unroll
      for (int nt = 0; nt < 2; ++nt)
        bf[nt] = *reinterpret_cast<const short8*>(
            Bsc + (wc * 32 + nt * 16 + lr) * 128 + ((kc * 64 + lk * 16) ^ sw));
      #pragma unroll
      for (int mt = 0; mt < 2; ++mt)
        #pragma unroll
        for (int nt = 0; nt < 2; ++nt)
          acc[mt][nt] = __builtin_amdgcn_mfma_f32_16x16x32_bf16(af[mt], bf[nt], acc[mt][nt], 0, 0, 0);
    }
    __syncthreads();
  }
  float* Co = Cp + (size_t)ks * 262144;
  #pragma unroll
  for (int mt = 0; mt < 2; ++mt)
    #pragma unroll
    for (int nt = 0; nt < 2; ++nt)
      #pragma unroll
      for (int r = 0; r < 4; ++r) {
        int row = wr * 32 + mt * 16 + lk * 4 + r;
        int col = wc * 32 + nt * 16 + lr;
        Co[(size_t)(m0 + row) * 1024 + n0 + col] = acc[mt][nt][r];
      }
}

// ---------------------------------------------------------------------------
// Tail: blocks 0..1023 o_reduce; 1024..1027 qk_importance; 1028..1031 v/o imp.
// grid = 1032, block = 256.
// ---------------------------------------------------------------------------
__global__ __launch_bounds__(256) void tail_all_kernel(
    const float* __restrict__ Op, const float* __restrict__ qkpart,
    const float* __restrict__ attn_out, float* __restrict__ out,
    float* __restrict__ qkout, float* __restrict__ vout, float* __restrict__ oout) {
  int b = blockIdx.x, t = threadIdx.x;
  if (b < 1024) {
    int i = b * 256 + t;               // 262144
    out[i] = Op[i] + Op[262144 + i] + Op[524288 + i] + Op[786432 + i];
  } else if (b < 1028) {
    int idx = (b - 1024) * 256 + t;    // 1024 = h*64+d
    int h = idx >> 6, d = idx & 63;
    float sum = 0.f;
    for (int j = 0; j < 128; ++j) sum += qkpart[((size_t)h * 128 + j) * 64 + d];
    qkout[idx] = sum;
  } else {
    int c = (b - 1028) * 256 + t;      // 1024
    float sum = 0.f;
    for (int s = 0; s < 256; ++s) sum += fabsf(attn_out[(size_t)s * 1024 + c]);
    vout[c] = sum;
    oout[c] = sum;
  }
}

// ---------------------------------------------------------------------------
extern "C" void kernel_launch(void* const* d_in, const int* in_sizes, int n_in,
                              void* d_out, int out_size, void* d_ws, size_t ws_size,
                              hipStream_t stream) {
  const float* X    = (const float*)d_in[0];   // hidden_states (1,256,1024)
  const float* cosp = (const float*)d_in[1];   // (1,256,64)
  const float* sinp = (const float*)d_in[2];   // (1,256,64)
  // d_in[3] attention_mask: causal, implemented analytically
  const float* Wq   = (const float*)d_in[4];   // (1024,1024)
  const float* Wk   = (const float*)d_in[5];   // (1024,512)
  const float* Wv   = (const float*)d_in[6];   // (1024,512)
  const float* Wo   = (const float*)d_in[7];   // (1024,1024)

  float* out  = (float*)d_out;                 // 262144
  float* pOut = out + 262144;                  // 1048576
  float* qki  = pOut + 1048576;                // 1024
  float* vi   = qki + 1024;                    // 1024
  float* oi   = vi + 1024;                     // 1024

  float* ws       = (float*)d_ws;
  float* QKV      = ws;                        // 524288 (s-major, 2048 cols: q|k|v)
  float* P2       = ws + 524288;               // 4096
  float* attn_out = ws + 528384;               // 262144
  float* qkpart   = ws + 790528;               // 131072
  ushort* aw2     = (ushort*)(ws + 921600);    // 1048576 ushort = 524288 floats
  float* scratch  = ws + 1445888;              // 1048576 (QKV partials x2; O partials x4)

  hipLaunchKernelGGL(gemm_qkv_kernel, dim3(256), dim3(256), 0, stream, X, Wq, Wk, Wv, scratch);
  hipLaunchKernelGGL(rope_reduce_kernel, dim3(1280), dim3(256), 0, stream, scratch, QKV, cosp, sinp);
  hipLaunchKernelGGL(qk_sm_kernel, dim3(256), dim3(256), 0, stream, QKV, pOut, aw2, P2);
  hipLaunchKernelGGL(pdiff_attnv_kernel, dim3(512), dim3(256), 0, stream, QKV, aw2, pOut, P2, qkpart, attn_out);
  hipLaunchKernelGGL(gemm_o_kernel, dim3(256), dim3(256), 0, stream, attn_out, Wo, scratch);
  hipLaunchKernelGGL(tail_all_kernel, dim3(1032), dim3(256), 0, stream, scratch, qkpart, attn_out, out, qki, vi, oi);
}

// Round 8
// 57.525 us; speedup vs baseline: 1.9994x; 1.0004x over previous
//
#include <hip/hip_runtime.h>
#include <math.h>

// Problem constants: B=1, S=256, HID=1024, H=16, KV=8, D=64, N_REP=2
#define SCALE 0.125f   // 1/sqrt(64)
#define LOG2E 1.44269504088896340736f

typedef short short8 __attribute__((ext_vector_type(8)));
typedef float floatx4 __attribute__((ext_vector_type(4)));

static __device__ __forceinline__ ushort f2bf(float x) {
  uint32_t b = __float_as_uint(x);
  uint32_t r = (b + 0x7FFFu + ((b >> 16) & 1u)) >> 16;   // RNE
  return (ushort)r;
}
static __device__ __forceinline__ float bf2f(ushort u) {
  return __uint_as_float(((uint32_t)u) << 16);
}

// ---------------------------------------------------------------------------
// MFMA bf16 GEMM 1: X(256x1024) @ [Wq|Wk|Wv](1024x2048) -> QKV partials.
// K-split 4. 64x64 tile, 4 waves (2x2), each wave 32x32 via 2x2 mfma 16x16x32.
// grid = 512 (4 ksplit * 128 tiles), block = 256.
// ---------------------------------------------------------------------------
__global__ __launch_bounds__(256) void gemm_qkv_kernel(
    const float* __restrict__ X, const float* __restrict__ Wq,
    const float* __restrict__ Wk, const float* __restrict__ Wv,
    float* __restrict__ Cp) {
  __shared__ ushort As[4096];
  __shared__ ushort Bs[4096];
  char* Asc = (char*)As;
  char* Bsc = (char*)Bs;
  const int bx = blockIdx.x;
  const int ks = bx >> 7;            // 0..3
  const int tile = bx & 127;         // 4 m-tiles x 32 n-tiles
  const int tile_n = tile & 31, tile_m = tile >> 5;
  const int n0 = tile_n * 64, m0 = tile_m * 64;
  const float* Bp; int ldb, bc0;
  if (n0 < 1024)      { Bp = Wq; ldb = 1024; bc0 = n0; }
  else if (n0 < 1536) { Bp = Wk; ldb = 512;  bc0 = n0 - 1024; }
  else                { Bp = Wv; ldb = 512;  bc0 = n0 - 1536; }
  const int t = threadIdx.x;
  const int arow = t >> 4, acg = t & 15;
  const int bng = t & 15;
  const int kbeg = ks * 256;
  float4 ra[4], rb0[2], rb1[2];
  auto LOAD = [&](int k0) {
    #pragma unroll
    for (int i = 0; i < 4; ++i)
      ra[i] = *reinterpret_cast<const float4*>(X + (size_t)(m0 + arow + 16 * i) * 1024 + k0 + acg * 4);
    #pragma unroll
    for (int i = 0; i < 2; ++i) {
      int k = 2 * ((t >> 4) + 16 * i);
      rb0[i] = *reinterpret_cast<const float4*>(Bp + (size_t)(k0 + k) * ldb + bc0 + bng * 4);
      rb1[i] = *reinterpret_cast<const float4*>(Bp + (size_t)(k0 + k + 1) * ldb + bc0 + bng * 4);
    }
  };
  LOAD(kbeg);
  const int wid = t >> 6, wr = wid >> 1, wc = wid & 1, lane = t & 63;
  const int lr = lane & 15, lk = lane >> 4;
  const int sw = (lr & 7) << 4;
  floatx4 acc[2][2];
  #pragma unroll
  for (int mt = 0; mt < 2; ++mt)
    #pragma unroll
    for (int nt = 0; nt < 2; ++nt)
      acc[mt][nt] = (floatx4){0.f, 0.f, 0.f, 0.f};
  for (int kt = 0; kt < 4; ++kt) {
    #pragma unroll
    for (int i = 0; i < 4; ++i) {
      int row = arow + 16 * i;
      ushort4 w;
      w.x = f2bf(ra[i].x); w.y = f2bf(ra[i].y); w.z = f2bf(ra[i].z); w.w = f2bf(ra[i].w);
      *reinterpret_cast<ushort4*>(Asc + row * 128 + ((acg * 8) ^ ((row & 7) << 4))) = w;
    }
    #pragma unroll
    for (int i = 0; i < 2; ++i) {
      int k = 2 * ((t >> 4) + 16 * i);
      const float* p0 = (const float*)&rb0[i];
      const float* p1 = (const float*)&rb1[i];
      #pragma unroll
      for (int j = 0; j < 4; ++j) {
        int n = bng * 4 + j;
        uint32_t v = (uint32_t)f2bf(p0[j]) | ((uint32_t)f2bf(p1[j]) << 16);
        *reinterpret_cast<uint32_t*>(Bsc + n * 128 + ((k * 2) ^ ((n & 7) << 4))) = v;
      }
    }
    __syncthreads();
    if (kt + 1 < 4) LOAD(kbeg + 64 * (kt + 1));
    #pragma unroll
    for (int kc = 0; kc < 2; ++kc) {
      short8 af[2], bf[2];
      #pragma unroll
      for (int mt = 0; mt < 2; ++mt)
        af[mt] = *reinterpret_cast<const short8*>(
            Asc + (wr * 32 + mt * 16 + lr) * 128 + ((kc * 64 + lk * 16) ^ sw));
      #pragma unroll
      for (int nt = 0; nt < 2; ++nt)
        bf[nt] = *reinterpret_cast<const short8*>(
            Bsc + (wc * 32 + nt * 16 + lr) * 128 + ((kc * 64 + lk * 16) ^ sw));
      #pragma unroll
      for (int mt = 0; mt < 2; ++mt)
        #pragma unroll
        for (int nt = 0; nt < 2; ++nt)
          acc[mt][nt] = __builtin_amdgcn_mfma_f32_16x16x32_bf16(af[mt], bf[nt], acc[mt][nt], 0, 0, 0);
    }
    __syncthreads();
  }
  float* Co = Cp + (size_t)ks * 524288;
  #pragma unroll
  for (int mt = 0; mt < 2; ++mt)
    #pragma unroll
    for (int nt = 0; nt < 2; ++nt)
      #pragma unroll
      for (int r = 0; r < 4; ++r) {
        int row = wr * 32 + mt * 16 + lk * 4 + r;
        int col = wc * 32 + nt * 16 + lr;
        Co[(size_t)(m0 + row) * 2048 + n0 + col] = acc[mt][nt][r];
      }
}

// ---------------------------------------------------------------------------
// Reduce the 4 QKV partials + RoPE on q/k heads. grid = 1280, block = 256.
// ---------------------------------------------------------------------------
__global__ __launch_bounds__(256) void rope_reduce_kernel(
    const float* __restrict__ Cp, float* __restrict__ QKV,
    const float* __restrict__ cs, const float* __restrict__ sn) {
  int idx = blockIdx.x * 256 + threadIdx.x;
  const float* P0 = Cp;
  const float* P1 = Cp + 524288;
  const float* P2p = Cp + 1048576;
  const float* P3 = Cp + 1572864;
  if (idx < 196608) {                 // 256 s * 24 heads * 32 pairs
    int dp = idx & 31;
    int head = (idx >> 5) % 24;       // 0..15 q heads, 16..23 k heads
    int s = idx / 768;
    int base = s * 2048 + head * 64;
    int a1 = base + dp, a2 = base + dp + 32;
    float x1 = P0[a1] + P1[a1] + P2p[a1] + P3[a1];
    float x2 = P0[a2] + P1[a2] + P2p[a2] + P3[a2];
    float c1 = cs[s * 64 + dp],      s1v = sn[s * 64 + dp];
    float c2 = cs[s * 64 + dp + 32], s2v = sn[s * 64 + dp + 32];
    QKV[a1] = x1 * c1 - x2 * s1v;   // q' = q*cos + rot_half(q)*sin
    QKV[a2] = x2 * c2 + x1 * s2v;
  } else {
    int i2 = idx - 196608;            // 131072 v elements
    int s = i2 >> 9, c = 1536 + (i2 & 511);
    int a = s * 2048 + c;
    QKV[a] = P0[a] + P1[a] + P2p[a] + P3[a];
  }
}

// ---------------------------------------------------------------------------
// Fused QK^T + softmax. One WG per (h, 16-row strip j). All 256 k-rows staged
// (fixed-trip unrolled loop -> pipelined loads; kills serial tail).
// Writes p (fp32), P2 = sum p^2, awf = fp32(aw*scale*log2e).
// grid = 256 (h*16 + j), block = 256.
// ---------------------------------------------------------------------------
__global__ __launch_bounds__(256) void qk_sm_kernel(
    const float* __restrict__ QKV, float* __restrict__ pOut,
    float* __restrict__ awf, float* __restrict__ P2) {
  __shared__ ushort ksh[16384];      // 32KB swizzled [t][d]
  __shared__ ushort qsh[1024];       // 2KB  swizzled [r][d]
  __shared__ float awsh[16][260];    // padded: conflict-free col reads
  char* kshc = (char*)ksh;
  char* qshc = (char*)qsh;
  const int h = blockIdx.x >> 4, j = blockIdx.x & 15;
  const int g = h >> 1;
  const int t = threadIdx.x;
  #pragma unroll
  for (int i = 0; i < 16; ++i) {     // stage ALL k rows (bf16, XOR swizzle)
    int row = (t >> 4) + 16 * i;
    int c = (t & 15) * 4;
    float4 kv = *reinterpret_cast<const float4*>(QKV + (size_t)row * 2048 + 1024 + g * 64 + c);
    ushort4 w;
    w.x = f2bf(kv.x); w.y = f2bf(kv.y); w.z = f2bf(kv.z); w.w = f2bf(kv.w);
    *reinterpret_cast<ushort4*>(kshc + row * 128 + ((c * 2) ^ ((row & 7) << 4))) = w;
  }
  { // stage q strip (16 rows)
    int row = t >> 4, c = (t & 15) * 4;
    float4 qv = *reinterpret_cast<const float4*>(QKV + (size_t)(16 * j + row) * 2048 + h * 64 + c);
    ushort4 w;
    w.x = f2bf(qv.x); w.y = f2bf(qv.y); w.z = f2bf(qv.z); w.w = f2bf(qv.w);
    *reinterpret_cast<ushort4*>(qshc + row * 128 + ((c * 2) ^ ((row & 7) << 4))) = w;
  }
  __syncthreads();
  const int w = t >> 6, lane = t & 63;
  const int lr = lane & 15, lk = lane >> 4;
  const int sw = (lr & 7) << 4;
  // MFMA: wave w handles n-tiles w, w+4, w+8, w+12 (those <= j)
  floatx4 acc[4];
  #pragma unroll
  for (int q4 = 0; q4 < 4; ++q4) acc[q4] = (floatx4){0.f, 0.f, 0.f, 0.f};
  #pragma unroll
  for (int q4 = 0; q4 < 4; ++q4) {
    int nt = w + 4 * q4;
    if (nt <= j) {
      #pragma unroll
      for (int kc = 0; kc < 2; ++kc) {
        short8 af = *reinterpret_cast<const short8*>(
            qshc + lr * 128 + ((kc * 64 + lk * 16) ^ sw));
        int tt = nt * 16 + lr;
        short8 bf = *reinterpret_cast<const short8*>(
            kshc + tt * 128 + ((kc * 64 + lk * 16) ^ ((tt & 7) << 4)));
        acc[q4] = __builtin_amdgcn_mfma_f32_16x16x32_bf16(af, bf, acc[q4], 0, 0, 0);
      }
    }
  }
  #pragma unroll
  for (int q4 = 0; q4 < 4; ++q4) {
    int nt = w + 4 * q4;
    if (nt <= j) {
      #pragma unroll
      for (int r = 0; r < 4; ++r)
        awsh[lk * 4 + r][nt * 16 + lr] = acc[q4][r];
    }
  }
  __syncthreads();
  // softmax: wave w -> rows 4w..4w+3 (s = 16j+row); lane covers 4 cols each
  for (int rr = 0; rr < 4; ++rr) {
    int row = 4 * w + rr;
    int s = 16 * j + row;
    float v[4], m = -3.0e38f;
    #pragma unroll
    for (int i = 0; i < 4; ++i) {
      int tc = lane + 64 * i;
      v[i] = (tc <= s) ? awsh[row][tc] * SCALE : -3.0e38f;
      m = fmaxf(m, v[i]);
    }
    #pragma unroll
    for (int off = 32; off; off >>= 1) m = fmaxf(m, __shfl_xor(m, off));
    float e[4], sum = 0.f;
    #pragma unroll
    for (int i = 0; i < 4; ++i) {
      int tc = lane + 64 * i;
      e[i] = (tc <= s) ? __expf(v[i] - m) : 0.f;
      sum += e[i];
    }
    #pragma unroll
    for (int off = 32; off; off >>= 1) sum += __shfl_xor(sum, off);
    float inv = 1.f / sum;
    float p2 = 0.f;
    size_t rowbase = ((size_t)h * 256 + s) * 256;
    #pragma unroll
    for (int i = 0; i < 4; ++i) {
      int tc = lane + 64 * i;
      float pv = e[i] * inv;
      pOut[rowbase + tc] = pv;
      p2 = fmaf(pv, pv, p2);
      if (tc <= s) awf[rowbase + tc] = v[i] * LOG2E;
    }
    #pragma unroll
    for (int off = 32; off; off >>= 1) p2 += __shfl_xor(p2, off);
    if (lane == 0) P2[h * 256 + s] = p2;
  }
}

// ---------------------------------------------------------------------------
// Merged p_diff + PV kernel. z2_t = awf_t - cd2*k[t,d] (base-2 domain);
//   e = exp2(z2); S1,S2,S3 as before; AV = sum p_t v[t,d].
// k|v packed one u32 per (t,d) in LDS -> 1 ds_read_b32 + 1 ds_read_b64 / iter.
// wave = (h, row-pair j/255-j). grid = 512 (8 g * 64 u), block = 256.
// ---------------------------------------------------------------------------
__global__ __launch_bounds__(256) void pdiff_attnv_kernel(
    const float* __restrict__ QKV, const float* __restrict__ awf,
    const float* __restrict__ p, const float* __restrict__ P2,
    float* __restrict__ qkpart, float* __restrict__ attn_out) {
  __shared__ uint32_t kvsh[16384];     // 64KB [t][d]: k bf16 lo | v bf16 hi
  __shared__ float2 rb[4][2][256];     // 16KB (awf_t, p_t) per wave-row
  int g = blockIdx.x >> 6;
  int u = blockIdx.x & 63;
  int t = threadIdx.x;
  #pragma unroll
  for (int i = 0; i < 16; ++i) {
    int fi = t + i * 256;              // 4096 float4 slots
    int tt = fi >> 4, c = (fi & 15) * 4;
    float4 kv = *reinterpret_cast<const float4*>(QKV + (size_t)tt * 2048 + 1024 + g * 64 + c);
    float4 vv = *reinterpret_cast<const float4*>(QKV + (size_t)tt * 2048 + 1536 + g * 64 + c);
    uint4 pk;
    pk.x = (uint32_t)f2bf(kv.x) | ((uint32_t)f2bf(vv.x) << 16);
    pk.y = (uint32_t)f2bf(kv.y) | ((uint32_t)f2bf(vv.y) << 16);
    pk.z = (uint32_t)f2bf(kv.z) | ((uint32_t)f2bf(vv.z) << 16);
    pk.w = (uint32_t)f2bf(kv.w) | ((uint32_t)f2bf(vv.w) << 16);
    *reinterpret_cast<uint4*>(&kvsh[tt * 64 + c]) = pk;
  }
  int w = t >> 6, lane = t & 63;
  int h = 2 * g + (w & 1);
  int jj = 2 * u + (w >> 1);
  for (int r = 0; r < 2; ++r) {
    int s = r ? 255 - jj : jj;
    size_t rowbase = ((size_t)h * 256 + s) * 256;
    #pragma unroll
    for (int i = 0; i < 4; ++i) {
      int idx = lane + i * 64;
      rb[w][r][idx] = make_float2(awf[rowbase + idx], p[rowbase + idx]);
    }
  }
  __syncthreads();
  float qk_acc = 0.f;
  for (int r = 0; r < 2; ++r) {
    int s = r ? 255 - jj : jj;
    float cd2 = (SCALE * LOG2E) * QKV[(size_t)s * 2048 + h * 64 + lane];
    float S1 = 0.f, S2 = 0.f, S3 = 0.f, AV = 0.f;
    const float2* rbr = rb[w][r];
    for (int tt = 0; tt <= s; ++tt) {
      uint32_t kv = kvsh[tt * 64 + lane];
      float kf = __uint_as_float(kv << 16);
      float vf = __uint_as_float(kv & 0xFFFF0000u);
      float2 ap = rbr[tt];
      float z2 = fmaf(-cd2, kf, ap.x);
      float e = exp2f(z2);
      S1 += e;
      S2 = fmaf(e, e, S2);
      S3 = fmaf(e, ap.y, S3);
      AV = fmaf(ap.y, vf, AV);
    }
    float inv = 1.f / S1;
    qk_acc += S2 * inv * inv - 2.f * S3 * inv + P2[h * 256 + s];
    attn_out[(size_t)s * 1024 + h * 64 + lane] = AV;
  }
  qkpart[((size_t)h * 128 + jj) * 64 + lane] = qk_acc;
}

// ---------------------------------------------------------------------------
// MFMA bf16 GEMM 2: attn_out(256x1024) @ Wo(1024x1024) -> out partials.
// K-split 8. grid = 512 (8 ks * 64 tiles), block = 256.
// ---------------------------------------------------------------------------
__global__ __launch_bounds__(256) void gemm_o_kernel(
    const float* __restrict__ A, const float* __restrict__ W,
    float* __restrict__ Cp) {
  __shared__ ushort As[4096];
  __shared__ ushort Bs[4096];
  char* Asc = (char*)As;
  char* Bsc = (char*)Bs;
  const int bx = blockIdx.x;
  const int ks = bx >> 6;            // 0..7
  const int tile = bx & 63;          // 4 m-tiles x 16 n-tiles
  const int tile_n = tile & 15, tile_m = tile >> 4;
  const int n0 = tile_n * 64, m0 = tile_m * 64;
  const int t = threadIdx.x;
  const int arow = t >> 4, acg = t & 15;
  const int bng = t & 15;
  const int kbeg = ks * 128;
  float4 ra[4], rb0[2], rb1[2];
  auto LOAD = [&](int k0) {
    #pragma unroll
    for (int i = 0; i < 4; ++i)
      ra[i] = *reinterpret_cast<const float4*>(A + (size_t)(m0 + arow + 16 * i) * 1024 + k0 + acg * 4);
    #pragma unroll
    for (int i = 0; i < 2; ++i) {
      int k = 2 * ((t >> 4) + 16 * i);
      rb0[i] = *reinterpret_cast<const float4*>(W + (size_t)(k0 + k) * 1024 + n0 + bng * 4);
      rb1[i] = *reinterpret_cast<const float4*>(W + (size_t)(k0 + k + 1) * 1024 + n0 + bng * 4);
    }
  };
  LOAD(kbeg);
  const int wid = t >> 6, wr = wid >> 1, wc = wid & 1, lane = t & 63;
  const int lr = lane & 15, lk = lane >> 4;
  const int sw = (lr & 7) << 4;
  floatx4 acc[2][2];
  #pragma unroll
  for (int mt = 0; mt < 2; ++mt)
    #pragma unroll
    for (int nt = 0; nt < 2; ++nt)
      acc[mt][nt] = (floatx4){0.f, 0.f, 0.f, 0.f};
  for (int kt = 0; kt < 2; ++kt) {
    #pragma unroll
    for (int i = 0; i < 4; ++i) {
      int row = arow + 16 * i;
      ushort4 w;
      w.x = f2bf(ra[i].x); w.y = f2bf(ra[i].y); w.z = f2bf(ra[i].z); w.w = f2bf(ra[i].w);
      *reinterpret_cast<ushort4*>(Asc + row * 128 + ((acg * 8) ^ ((row & 7) << 4))) = w;
    }
    #pragma unroll
    for (int i = 0; i < 2; ++i) {
      int k = 2 * ((t >> 4) + 16 * i);
      const float* p0 = (const float*)&rb0[i];
      const float* p1 = (const float*)&rb1[i];
      #pragma unroll
      for (int j = 0; j < 4; ++j) {
        int n = bng * 4 + j;
        uint32_t v = (uint32_t)f2bf(p0[j]) | ((uint32_t)f2bf(p1[j]) << 16);
        *reinterpret_cast<uint32_t*>(Bsc + n * 128 + ((k * 2) ^ ((n & 7) << 4))) = v;
      }
    }
    __syncthreads();
    if (kt + 1 < 2) LOAD(kbeg + 64 * (kt + 1));
    #pragma unroll
    for (int kc = 0; kc < 2; ++kc) {
      short8 af[2], bf[2];
      #pragma unroll
      for (int mt = 0; mt < 2; ++mt)
        af[mt] = *reinterpret_cast<const short8*>(
            Asc + (wr * 32 + mt * 16 + lr) * 128 + ((kc * 64 + lk * 16) ^ sw));
      #pragma unroll
      for (int nt = 0; nt < 2; ++nt)
        bf[nt] = *reinterpret_cast<const short8*>(
            Bsc + (wc * 32 + nt * 16 + lr) * 128 + ((kc * 64 + lk * 16) ^ sw));
      #pragma unroll
      for (int mt = 0; mt < 2; ++mt)
        #pragma unroll
        for (int nt = 0; nt < 2; ++nt)
          acc[mt][nt] = __builtin_amdgcn_mfma_f32_16x16x32_bf16(af[mt], bf[nt], acc[mt][nt], 0, 0, 0);
    }
    __syncthreads();
  }
  float* Co = Cp + (size_t)ks * 262144;
  #pragma unroll
  for (int mt = 0; mt < 2; ++mt)
    #pragma unroll
    for (int nt = 0; nt < 2; ++nt)
      #pragma unroll
      for (int r = 0; r < 4; ++r) {
        int row = wr * 32 + mt * 16 + lk * 4 + r;
        int col = wc * 32 + nt * 16 + lr;
        Co[(size_t)(m0 + row) * 1024 + n0 + col] = acc[mt][nt][r];
      }
}

// ---------------------------------------------------------------------------
// Tail: blocks 0..1023 o_reduce (8 partials); 1024..1027 qk_importance;
// 1028..1031 v/o importance. grid = 1032, block = 256.
// ---------------------------------------------------------------------------
__global__ __launch_bounds__(256) void tail_all_kernel(
    const float* __restrict__ Op, const float* __restrict__ qkpart,
    const float* __restrict__ attn_out, float* __restrict__ out,
    float* __restrict__ qkout, float* __restrict__ vout, float* __restrict__ oout) {
  int b = blockIdx.x, t = threadIdx.x;
  if (b < 1024) {
    int i = b * 256 + t;               // 262144
    float s = 0.f;
    #pragma unroll
    for (int k = 0; k < 8; ++k) s += Op[(size_t)k * 262144 + i];
    out[i] = s;
  } else if (b < 1028) {
    int idx = (b - 1024) * 256 + t;    // 1024 = h*64+d
    int h = idx >> 6, d = idx & 63;
    float sum = 0.f;
    for (int j = 0; j < 128; ++j) sum += qkpart[((size_t)h * 128 + j) * 64 + d];
    qkout[idx] = sum;
  } else {
    int c = (b - 1028) * 256 + t;      // 1024
    float sum = 0.f;
    for (int s = 0; s < 256; ++s) sum += fabsf(attn_out[(size_t)s * 1024 + c]);
    vout[c] = sum;
    oout[c] = sum;
  }
}

// ---------------------------------------------------------------------------
extern "C" void kernel_launch(void* const* d_in, const int* in_sizes, int n_in,
                              void* d_out, int out_size, void* d_ws, size_t ws_size,
                              hipStream_t stream) {
  const float* X    = (const float*)d_in[0];   // hidden_states (1,256,1024)
  const float* cosp = (const float*)d_in[1];   // (1,256,64)
  const float* sinp = (const float*)d_in[2];   // (1,256,64)
  // d_in[3] attention_mask: causal, implemented analytically
  const float* Wq   = (const float*)d_in[4];   // (1024,1024)
  const float* Wk   = (const float*)d_in[5];   // (1024,512)
  const float* Wv   = (const float*)d_in[6];   // (1024,512)
  const float* Wo   = (const float*)d_in[7];   // (1024,1024)

  float* out  = (float*)d_out;                 // 262144
  float* pOut = out + 262144;                  // 1048576
  float* qki  = pOut + 1048576;                // 1024
  float* vi   = qki + 1024;                    // 1024
  float* oi   = vi + 1024;                     // 1024

  float* ws       = (float*)d_ws;
  float* QKV      = ws;                        // 524288 (s-major, 2048 cols: q|k|v)
  float* P2       = ws + 524288;               // 4096
  float* attn_out = ws + 528384;               // 262144
  float* qkpart   = ws + 790528;               // 131072
  float* awf      = ws + 921600;               // 1048576 fp32 (aw*scale*log2e)
  float* scratch  = ws + 1970176;              // 2097152 (QKV partials x4; O partials x8)

  hipLaunchKernelGGL(gemm_qkv_kernel, dim3(512), dim3(256), 0, stream, X, Wq, Wk, Wv, scratch);
  hipLaunchKernelGGL(rope_reduce_kernel, dim3(1280), dim3(256), 0, stream, scratch, QKV, cosp, sinp);
  hipLaunchKernelGGL(qk_sm_kernel, dim3(256), dim3(256), 0, stream, QKV, pOut, awf, P2);
  hipLaunchKernelGGL(pdiff_attnv_kernel, dim3(512), dim3(256), 0, stream, QKV, awf, pOut, P2, qkpart, attn_out);
  hipLaunchKernelGGL(gemm_o_kernel, dim3(512), dim3(256), 0, stream, attn_out, Wo, scratch);
  hipLaunchKernelGGL(tail_all_kernel, dim3(1032), dim3(256), 0, stream, scratch, qkpart, attn_out, out, qki, vi, oi);
}